// Round 7
// baseline (526.036 us; speedup 1.0000x reference)
//
#include <hip/hip_runtime.h>
#include <hip/hip_bf16.h>
#include <cstdint>
#include <cstddef>

typedef __bf16 bf16_t;
typedef __bf16 bf16x8 __attribute__((ext_vector_type(8)));
typedef __bf16 bf16x4 __attribute__((ext_vector_type(4)));
typedef float  f32x4  __attribute__((ext_vector_type(4)));

static constexpr int Bb = 4, Ss = 1024, Ee = 1024, Hh = 32, Dd = 32;
static constexpr int Ntok = Bb * Ss;   // 4096
static constexpr int E3   = 3 * Ee;    // 3072
static constexpr float SCALE2 = 0.25506060570135506f;   // (1/sqrt(32)) * log2(e)

__device__ __forceinline__ void gl_lds16(const void* g, void* l) {
  __builtin_amdgcn_global_load_lds(
      (const __attribute__((address_space(1))) void*)g,
      (__attribute__((address_space(3))) void*)l, 16, 0, 0);
}
__device__ __forceinline__ float fexp2(float x) { return __builtin_amdgcn_exp2f(x); }

// ---------------------------------------------------------------- fused f32->bf16 conversions
__global__ __launch_bounds__(256) void conv_all(const float* __restrict__ x,  const float* __restrict__ qw,
                                                const float* __restrict__ kw, const float* __restrict__ vw,
                                                const float* __restrict__ inw,const float* __restrict__ ow,
                                                const float* __restrict__ fw,
                                                bf16_t* xb, bf16_t* qb, bf16_t* kb, bf16_t* vb,
                                                bf16_t* inb, bf16_t* ob, bf16_t* fb) {
  const int i = blockIdx.x * 256 + threadIdx.x;
  const float* src; bf16_t* dst; int base;
  if      (i < 1048576) { src = x;   dst = xb;  base = 0; }
  else if (i < 1310720) { src = qw;  dst = qb;  base = 1048576; }
  else if (i < 1572864) { src = kw;  dst = kb;  base = 1310720; }
  else if (i < 1835008) { src = vw;  dst = vb;  base = 1572864; }
  else if (i < 2621440) { src = inw; dst = inb; base = 1835008; }
  else if (i < 2883584) { src = ow;  dst = ob;  base = 2621440; }
  else                  { src = fw;  dst = fb;  base = 2883584; }
  const int j = i - base;
  const float4 v = *(const float4*)(src + (size_t)j * 4);
  bf16x4 o = {(bf16_t)v.x, (bf16_t)v.y, (bf16_t)v.z, (bf16_t)v.w};
  *(bf16x4*)(dst + (size_t)j * 4) = o;
}

// ---------------------------------------------------------------- bias concat q_b|k_b|v_b
__global__ __launch_bounds__(256) void prepb(const float* __restrict__ qb, const float* __restrict__ kb,
                                             const float* __restrict__ vb, float* __restrict__ o) {
  const int i = blockIdx.x * 256 + threadIdx.x;
  o[i] = (i < 1024) ? qb[i] : (i < 2048) ? kb[i - 1024] : vb[i - 2048];
}

// ---------------------------------------------------------------- bias_c[n] = fin_b[n] + sum_j fin_w[n][j]*out_b[j]
__global__ __launch_bounds__(256) void biasck(const float* __restrict__ fw, const float* __restrict__ ob,
                                              const float* __restrict__ fb, float* __restrict__ bc) {
  const int t = threadIdx.x;
  const int n = blockIdx.x * 64 + (t >> 2), p = t & 3;
  const float* row = fw + (size_t)n * 1024 + p * 256;
  const float* obp = ob + p * 256;
  float s = 0.f;
  for (int j = 0; j < 256; ++j) s += row[j] * obp[j];
  s += __shfl_xor(s, 1);
  s += __shfl_xor(s, 2);
  if (p == 0) bc[n] = s + fb[n];
}

// ---------------------------------------------------------------- mean over S
__global__ __launch_bounds__(256) void colmean_part(const float* __restrict__ x,
                                                    float* __restrict__ part) {
  const int b = blockIdx.y, sc = blockIdx.x;
  const float* base = x + ((size_t)b * Ss + sc * 32) * Ee;
  for (int k = 0; k < 4; ++k) {
    const int e = threadIdx.x + k * 256;
    float s = 0.f;
    for (int i = 0; i < 32; ++i) s += base[(size_t)i * Ee + e];
    part[((size_t)sc * 4 + b) * Ee + e] = s;
  }
}
__global__ __launch_bounds__(256) void colmean_fin(const float* __restrict__ part,
                                                   float* __restrict__ xm) {
  const int idx = blockIdx.x * 256 + threadIdx.x;
  const int b = idx >> 10, e = idx & 1023;
  float s = 0.f;
  for (int sc = 0; sc < 32; ++sc) s += part[((size_t)sc * 4 + b) * Ee + e];
  xm[idx] = s * (1.0f / 1024.0f);
}

// ---------------------------------------------------------------- h = relu(xmean @ w1^T + b1)
__global__ __launch_bounds__(256) void hgemm(const float* __restrict__ xm,
                                             const float* __restrict__ w1,
                                             const float* __restrict__ b1,
                                             float* __restrict__ hout) {
  __shared__ float xl[4 * 1024];
  for (int i = threadIdx.x; i < 4096; i += 256) xl[i] = xm[i];
  __syncthreads();
  const int j = blockIdx.x * 64 + (threadIdx.x >> 2);
  const int b = threadIdx.x & 3;
  const float* wr = w1 + (size_t)j * Ee;
  const float* xr = xl + b * 1024;
  float s = 0.f;
  for (int e = 0; e < 1024; ++e) s += xr[e] * wr[e];
  s += b1[j];
  hout[b * 1024 + j] = fmaxf(s, 0.f);
}

// ---------------------------------------------------------------- phase = cos(h @ w2^T + b2)
__global__ __launch_bounds__(128) void phasek(const float* __restrict__ hin,
                                              const float* __restrict__ w2,
                                              const float* __restrict__ b2,
                                              float* __restrict__ ph) {
  const int t = threadIdx.x;
  const int b = t >> 5, hh = t & 31;
  const float* hr = hin + b * 1024;
  const float* wr = w2 + (size_t)hh * Ee;
  float s = 0.f;
  for (int j = 0; j < 1024; ++j) s += hr[j] * wr[j];
  ph[t] = cosf(s + b2[hh]);
}

// ---------------------------------------------------------------- bf16 1024x1024 transpose
__global__ __launch_bounds__(256) void transpose1024(const bf16_t* __restrict__ in,
                                                     bf16_t* __restrict__ out) {
  __shared__ bf16_t t[64][72];
  const int jt = threadIdx.x >> 2, k16 = (threadIdx.x & 3) * 16;
  const int r0 = blockIdx.y * 64, c0 = blockIdx.x * 64;
  const bf16x8 a = *(const bf16x8*)(in + (size_t)(r0 + jt) * 1024 + c0 + k16);
  const bf16x8 b = *(const bf16x8*)(in + (size_t)(r0 + jt) * 1024 + c0 + k16 + 8);
  *(bf16x8*)&t[jt][k16] = a;
  *(bf16x8*)&t[jt][k16 + 8] = b;
  __syncthreads();
  bf16x8 v0, v1;
#pragma unroll
  for (int m = 0; m < 8; ++m) v0[m] = t[k16 + m][jt];
#pragma unroll
  for (int m = 0; m < 8; ++m) v1[m] = t[k16 + 8 + m][jt];
  *(bf16x8*)(out + (size_t)(c0 + jt) * 1024 + r0 + k16) = v0;
  *(bf16x8*)(out + (size_t)(c0 + jt) * 1024 + r0 + k16 + 8) = v1;
}

// ---------------------------------------------------------------- GEMM 128^2 (m97 structure)
// MODE 0: bf16 | 5: fp32, split-K (A2/Bt2 for k>=1024)
template <int MODE>
__global__ __launch_bounds__(256) void gemm_bt(const bf16_t* __restrict__ A,
                                               const bf16_t* __restrict__ A2,
                                               const bf16_t* __restrict__ Bt,
                                               const bf16_t* __restrict__ Bt2,
                                               const float* __restrict__ bias,
                                               void* __restrict__ Cout,
                                               int K, int lda, int ldb, int ldc) {
  __shared__ bf16_t As[128 * 32];
  __shared__ bf16_t Bs[128 * 32];
  const int tid = threadIdx.x;
  const int w = tid >> 6, lane = tid & 63;
  const int nwg = gridDim.x * gridDim.y;
  int flat = blockIdx.y * gridDim.x + blockIdx.x;
  flat = (flat & 7) * (nwg >> 3) + (flat >> 3);
  const int m0 = (flat / gridDim.x) * 128, n0 = (flat % gridDim.x) * 128;
  const int wr = (w >> 1) * 64, wc = (w & 1) * 64;
  const int r_ld = lane >> 2, c_ld = (lane & 3) * 8;
  const int rr = lane & 15, kk8 = (lane >> 4) * 8;
  f32x4 acc[4][4];
#pragma unroll
  for (int m = 0; m < 4; ++m)
#pragma unroll
    for (int n = 0; n < 4; ++n) acc[m][n] = f32x4{0.f, 0.f, 0.f, 0.f};

  for (int kt = 0; kt < K; kt += 32) {
    const bf16_t* Ak = A;
    const bf16_t* Bk = Bt;
    int kk = kt;
    if constexpr (MODE == 5) {
      if (kt >= 1024) { Ak = A2; Bk = Bt2; kk = kt - 1024; }
    }
#pragma unroll
    for (int j = 0; j < 2; ++j) {
      const int r0 = w * 16 + j * 64;
      gl_lds16(Ak + (size_t)(m0 + r0 + r_ld) * lda + kk + c_ld, &As[r0 * 32]);
      gl_lds16(Bk + (size_t)(n0 + r0 + r_ld) * ldb + kk + c_ld, &Bs[r0 * 32]);
    }
    __syncthreads();
    bf16x8 af[4], bfr[4];
#pragma unroll
    for (int m = 0; m < 4; ++m) af[m] = *(const bf16x8*)&As[(wr + m * 16 + rr) * 32 + kk8];
#pragma unroll
    for (int n = 0; n < 4; ++n) bfr[n] = *(const bf16x8*)&Bs[(wc + n * 16 + rr) * 32 + kk8];
#pragma unroll
    for (int m = 0; m < 4; ++m)
#pragma unroll
      for (int n = 0; n < 4; ++n)
        acc[m][n] = __builtin_amdgcn_mfma_f32_16x16x32_bf16(af[m], bfr[n], acc[m][n], 0, 0, 0);
    __syncthreads();
  }

  const int rr4 = (lane >> 4) * 4, cc = lane & 15;
#pragma unroll
  for (int m = 0; m < 4; ++m) {
#pragma unroll
    for (int n = 0; n < 4; ++n) {
      const int gr0 = m0 + wr + m * 16 + rr4;
      const int gc = n0 + wc + n * 16 + cc;
      const float bb = bias ? bias[gc] : 0.f;
#pragma unroll
      for (int i = 0; i < 4; ++i) {
        const size_t idx = (size_t)(gr0 + i) * ldc + gc;
        float v = acc[m][n][i] + bb;
        if constexpr (MODE == 5) ((float*)Cout)[idx] = v;
        else ((bf16_t*)Cout)[idx] = (bf16_t)v;
      }
    }
  }
}

// ---------------------------------------------------------------- GEMM 256^2, 8-phase (HK-style)
// BM=BN=256, BK=64 (2 k-slices of 32), 8 waves (2M x 4N), K=1024 fixed (16 tiles, 8 iters).
// LDS: 8 slices [buf][op][ks] of 16KB ([256 rows][4 slots of 16B], slot ^= row&3) = 128KB.
// Counted vmcnt(4) at phases 4/8 only; raw s_barrier + lgkmcnt(0) + sched_barrier(0).
// MODE 0: bf16 + bias | 4: bf16 * phase (cols < 2048) + bias
static constexpr int G256_LDS = 131072;

#define GPHASE(BUF, KS, FH, STAGE, VM) do {                                             \
    bf16x8 afr[4], bfr[4];                                                              \
    {  char* sA = slice(BUF, 0, KS);                                                    \
       char* sB = slice(BUF, 1, KS);                                                    \
      _Pragma("unroll") for (int mi = 0; mi < 4; ++mi)                                  \
        afr[mi] = *(const bf16x8*)(sA + (wm * 128 + FH * 64 + mi * 16 + r) * 64 + xg);  \
      _Pragma("unroll") for (int ni = 0; ni < 4; ++ni)                                  \
        bfr[ni] = *(const bf16x8*)(sB + (wn * 64 + ni * 16 + r) * 64 + xg); }           \
    STAGE;                                                                              \
    __builtin_amdgcn_s_barrier();                                                       \
    asm volatile("s_waitcnt lgkmcnt(0)" ::: "memory");                                  \
    __builtin_amdgcn_sched_barrier(0);                                                  \
    __builtin_amdgcn_s_setprio(1);                                                      \
    _Pragma("unroll") for (int mi = 0; mi < 4; ++mi)                                    \
      _Pragma("unroll") for (int ni = 0; ni < 4; ++ni)                                  \
        acc[FH * 4 + mi][ni] = __builtin_amdgcn_mfma_f32_16x16x32_bf16(                 \
            afr[mi], bfr[ni], acc[FH * 4 + mi][ni], 0, 0, 0);                           \
    __builtin_amdgcn_s_setprio(0);                                                      \
    VM;                                                                                 \
    __builtin_amdgcn_s_barrier();                                                       \
    __builtin_amdgcn_sched_barrier(0);                                                  \
  } while (0)

#define VMC4 asm volatile("s_waitcnt vmcnt(4)" ::: "memory")
#define VMC0 asm volatile("s_waitcnt vmcnt(0)" ::: "memory")

template <int MODE>
__global__ __launch_bounds__(512, 1) void gemm256(const bf16_t* __restrict__ A,
                                                  const bf16_t* __restrict__ Bt,
                                                  const float* __restrict__ bias,
                                                  void* __restrict__ Cout,
                                                  const float* __restrict__ phase,
                                                  int lda, int ldb, int ldc) {
  extern __shared__ char sm[];
  auto slice = [&](int bu, int op, int ks) -> char* {
    return sm + ((((bu << 1) | op) << 1 | ks) << 14);
  };
  const int tid = threadIdx.x, lane = tid & 63, w = tid >> 6;
  const int g = lane >> 4, r = lane & 15;
  const int wm = w >> 2, wn = w & 3;
  const int xg = ((g ^ (r & 3)) << 4);
  const int nwg = gridDim.x * gridDim.y;   // % 8 == 0
  int flat = blockIdx.y * gridDim.x + blockIdx.x;
  flat = (flat & 7) * (nwg >> 3) + (flat >> 3);
  const int m0 = (flat / gridDim.x) * 256, n0 = (flat % gridDim.x) * 256;

  // stage one operand k-slice of tile T into [buf][op][ks]: 2 gl_lds per thread
  auto stage2 = [&](int buf, int op, int ks, int T) {
    const bf16_t* src = op ? Bt : A;
    const int ld = op ? ldb : lda;
    const int b0 = op ? n0 : m0;
    char* dstb = slice(buf, op, ks);
#pragma unroll
    for (int hf = 0; hf < 2; ++hf) {
      const int row = hf * 128 + w * 16 + (lane >> 2);
      const int si = lane & 3;
      gl_lds16(src + (size_t)(b0 + row) * ld + T * 64 + ks * 32 + ((si ^ (row & 3)) << 3),
               dstb + hf * 8192 + w * 1024);
    }
  };

  f32x4 acc[8][4];
#pragma unroll
  for (int j = 0; j < 8; ++j)
#pragma unroll
    for (int n = 0; n < 4; ++n) acc[j][n] = f32x4{0.f, 0.f, 0.f, 0.f};

  // prologue: tile0 full -> buf0, tile1 ks0 -> buf1
  stage2(0, 0, 0, 0); stage2(0, 1, 0, 0); stage2(0, 0, 1, 0); stage2(0, 1, 1, 0);
  stage2(1, 0, 0, 1); stage2(1, 1, 0, 1);
  VMC4;
  __builtin_amdgcn_s_barrier();
  __builtin_amdgcn_sched_barrier(0);

  for (int i = 0; i < 8; ++i) {
    const int t1 = 2 * i + 1, t2 = 2 * i + 2, t3 = 2 * i + 3;
    GPHASE(0, 0, 0, { stage2(1, 0, 1, t1); }, );                       // ph1
    GPHASE(0, 0, 1, { stage2(1, 1, 1, t1); }, );                       // ph2
    GPHASE(0, 1, 0, { if (i < 7) stage2(0, 0, 0, t2); }, );            // ph3
    GPHASE(0, 1, 1, { if (i < 7) stage2(0, 1, 0, t2); },
           { if (i < 7) { VMC4; } else { VMC0; } });                   // ph4
    GPHASE(1, 0, 0, { if (i < 7) stage2(0, 0, 1, t2); }, );            // ph5
    GPHASE(1, 0, 1, { if (i < 7) stage2(0, 1, 1, t2); }, );            // ph6
    GPHASE(1, 1, 0, { if (i < 7) stage2(1, 0, 0, t3); }, );            // ph7
    GPHASE(1, 1, 1, { if (i < 7) stage2(1, 1, 0, t3); },
           { if (i < 7) { VMC4; } });                                  // ph8
  }

  // epilogue: C/D mapping col=lane&15, row=(lane>>4)*4+ii
#pragma unroll
  for (int j = 0; j < 8; ++j) {
#pragma unroll
    for (int ni = 0; ni < 4; ++ni) {
      const int gr0 = m0 + wm * 128 + (j >> 2) * 64 + (j & 3) * 16 + g * 4;
      const int gc = n0 + wn * 64 + ni * 16 + r;
      const float bb = bias[gc];
#pragma unroll
      for (int ii = 0; ii < 4; ++ii) {
        float v = acc[j][ni][ii] + bb;
        if constexpr (MODE == 4) {
          if (gc < 2048) v *= phase[(((gr0 + ii) >> 10) << 5) + ((gc >> 5) & 31)];
        }
        ((bf16_t*)Cout)[(size_t)(gr0 + ii) * ldc + gc] = (bf16_t)v;
      }
    }
  }
}

// ---------------------------------------------------------------- V transpose: [token, e] -> [bh][d][s]
__global__ __launch_bounds__(256) void transpose_v(const bf16_t* __restrict__ src, int rs,
                                                   bf16_t* __restrict__ dst) {
  __shared__ bf16_t buf[128 * 33];
  const int bh = blockIdx.y, b = bh >> 5, h = bh & 31;
  const int s0 = blockIdx.x * 128;
  const bf16_t* in = src + ((size_t)b * Ss + s0) * rs + h * 32;
  for (int e = threadIdx.x; e < 128 * 32; e += 256) {
    const int s = e >> 5, d = e & 31;
    buf[s * 33 + d] = in[(size_t)s * rs + d];
  }
  __syncthreads();
  bf16_t* out = dst + (size_t)bh * (Dd * Ss) + s0;
  for (int e = threadIdx.x; e < 128 * 32; e += 256) {
    const int d = e >> 7, s = e & 127;
    out[(size_t)d * Ss + s] = buf[s * 33 + d];
  }
}

// ---------------------------------------------------------------- fused attention
static constexpr int K_PLANE_B = 16400;
static constexpr int V_OFF_B   = 4 * K_PLANE_B;
static constexpr int V_ROW_B   = 2064;
static constexpr int P_OFF_B   = V_OFF_B + 32 * V_ROW_B;
static constexpr int P_WAVE_B  = 2304;
static constexpr int ATTN_LDS  = P_OFF_B + 8 * P_WAVE_B;  // 150080

template <int WRITE_P>
__global__ __launch_bounds__(512) void attn_fused(const bf16_t* __restrict__ Qm,
                                                  const bf16_t* __restrict__ Km, int rs,
                                                  const bf16_t* __restrict__ Vt,
                                                  float* __restrict__ Pout,
                                                  bf16_t* __restrict__ ctx, float scale2) {
  extern __shared__ char smem[];
  char* Kl = smem;
  char* Vl = smem + V_OFF_B;
  const int tid = threadIdx.x, lane = tid & 63, w = tid >> 6;
  const int g = lane >> 4, r = lane & 15;
  int flat = blockIdx.y * 8 + blockIdx.x;
  flat = (flat & 7) * 128 + (flat >> 3);
  const int bh = flat >> 3, xb = flat & 7;
  const int b = bh >> 5, h = bh & 31;
  char* myP = smem + P_OFF_B + w * P_WAVE_B;

  {
    const bf16_t* Kbase = Km + (size_t)b * Ss * rs + h * 32;
    const int pg = w >> 1, hh = w & 1;
#pragma unroll
    for (int c = 0; c < 8; ++c) {
      const int row0 = hh * 512 + c * 64;
      gl_lds16(Kbase + (size_t)(row0 + lane) * rs + pg * 8, Kl + pg * K_PLANE_B + row0 * 16);
    }
  }
  {
    const bf16_t* vsrc = Vt + (size_t)bh * (Dd * Ss);
#pragma unroll
    for (int rr2 = 0; rr2 < 4; ++rr2) {
      const int row = w * 4 + rr2;
#pragma unroll
      for (int c = 0; c < 2; ++c)
        gl_lds16(vsrc + (size_t)row * Ss + c * 512 + lane * 8, Vl + row * V_ROW_B + c * 1024);
    }
  }
  const int qrow0 = xb * 128 + w * 16;
  const bf16x8 qraw = *(const bf16x8*)(Qm + ((size_t)b * Ss + qrow0 + r) * rs + h * 32 + g * 8);
  bf16x8 qf;
#pragma unroll
  for (int i = 0; i < 8; ++i) qf[i] = (bf16_t)((float)qraw[i] * scale2);
  __syncthreads();

  const f32x4 zero = {0.f, 0.f, 0.f, 0.f};
  float lsum = 0.f, rinv = 1.f;

  if constexpr (WRITE_P) {
    for (int kt = 0; kt < 16; ++kt) {
#pragma unroll
      for (int n = 0; n < 4; ++n) {
        const int key = kt * 64 + n * 16 + r;
        const bf16x8 kf = *(const bf16x8*)(Kl + g * K_PLANE_B + key * 16);
        const f32x4 s = __builtin_amdgcn_mfma_f32_16x16x32_bf16(kf, qf, zero, 0, 0, 0);
#pragma unroll
        for (int i = 0; i < 4; ++i) lsum += fexp2(s[i]);
      }
    }
    lsum += __shfl_xor(lsum, 16);
    lsum += __shfl_xor(lsum, 32);
    rinv = 1.0f / lsum;
  }

  f32x4 acc2[2] = {zero, zero};
  const size_t pbase = (size_t)bh * Ss * Ss;

  for (int kt = 0; kt < 16; ++kt) {
    float p[4][4];
#pragma unroll
    for (int n = 0; n < 4; ++n) {
      const int key = kt * 64 + n * 16 + r;
      const bf16x8 kf = *(const bf16x8*)(Kl + g * K_PLANE_B + key * 16);
      const f32x4 s = __builtin_amdgcn_mfma_f32_16x16x32_bf16(kf, qf, zero, 0, 0, 0);
#pragma unroll
      for (int i = 0; i < 4; ++i) {
        float e = fexp2(s[i]);
        if constexpr (WRITE_P) e *= rinv;
        else lsum += e;
        p[n][i] = e;
      }
      bf16x4 pw = {(bf16_t)p[n][0], (bf16_t)p[n][1], (bf16_t)p[n][2], (bf16_t)p[n][3]};
      *(bf16x4*)(myP + r * 144 + (n * 16 + g * 4) * 2) = pw;
      if constexpr (WRITE_P) {
        f32x4 w4 = {p[n][0], p[n][1], p[n][2], p[n][3]};
        *(f32x4*)&Pout[pbase + (size_t)(qrow0 + r) * Ss + kt * 64 + n * 16 + 4 * g] = w4;
      }
    }
#pragma unroll
    for (int c = 0; c < 2; ++c) {
      const bf16x8 pa = *(const bf16x8*)(myP + r * 144 + (c * 32 + 8 * g) * 2);
#pragma unroll
      for (int dn = 0; dn < 2; ++dn) {
        const bf16x8 vf = *(const bf16x8*)(Vl + (dn * 16 + r) * V_ROW_B +
                                           (kt * 64 + c * 32 + g * 8) * 2);
        acc2[dn] = __builtin_amdgcn_mfma_f32_16x16x32_bf16(vf, pa, acc2[dn], 0, 0, 0);
      }
    }
  }

  if constexpr (!WRITE_P) {
    lsum += __shfl_xor(lsum, 16);
    lsum += __shfl_xor(lsum, 32);
    rinv = 1.0f / lsum;
#pragma unroll
    for (int dn = 0; dn < 2; ++dn)
#pragma unroll
      for (int i = 0; i < 4; ++i) acc2[dn][i] *= rinv;
  }

  float* Ct = (float*)myP;
#pragma unroll
  for (int dn = 0; dn < 2; ++dn)
#pragma unroll
    for (int i = 0; i < 4; ++i)
      Ct[r * 36 + dn * 16 + 4 * g + i] = acc2[dn][i];
  const int q2 = lane >> 2, pt = lane & 3;
  const f32x4 ca = *(const f32x4*)(myP + q2 * 144 + pt * 32);
  const f32x4 cb = *(const f32x4*)(myP + q2 * 144 + pt * 32 + 16);
  bf16x8 cv = {(bf16_t)ca[0], (bf16_t)ca[1], (bf16_t)ca[2], (bf16_t)ca[3],
               (bf16_t)cb[0], (bf16_t)cb[1], (bf16_t)cb[2], (bf16_t)cb[3]};
  *(bf16x8*)&ctx[((size_t)b * Ss + qrow0 + q2) * Ee + h * 32 + pt * 8] = cv;
}

// ================================================================ launcher
extern "C" void kernel_launch(void* const* d_in, const int* in_sizes, int n_in,
                              void* d_out, int out_size, void* d_ws, size_t ws_size,
                              hipStream_t stream) {
  const float* x     = (const float*)d_in[0];
  const float* q_w   = (const float*)d_in[1];
  const float* q_b   = (const float*)d_in[2];
  const float* k_w   = (const float*)d_in[3];
  const float* k_b   = (const float*)d_in[4];
  const float* v_w   = (const float*)d_in[5];
  const float* v_b   = (const float*)d_in[6];
  const float* ph_w1 = (const float*)d_in[7];
  const float* ph_b1 = (const float*)d_in[8];
  const float* ph_w2 = (const float*)d_in[9];
  const float* ph_b2 = (const float*)d_in[10];
  const float* in_w  = (const float*)d_in[11];
  const float* in_b  = (const float*)d_in[12];
  const float* out_w = (const float*)d_in[13];
  const float* out_b = (const float*)d_in[14];
  const float* fin_w = (const float*)d_in[15];
  const float* fin_b = (const float*)d_in[16];

  float* outp = (float*)d_out;
  float* attn_out = outp + (size_t)Ntok * Ee;

  char* ws = (char*)d_ws;
  size_t off = 0;
  auto alloc = [&](size_t bytes) -> void* {
    void* p = ws + off;
    off += (bytes + 255) & ~(size_t)255;
    return p;
  };
  bf16_t* x_bf  = (bf16_t*)alloc((size_t)Ntok * Ee * 2);
  bf16_t* wqkv  = (bf16_t*)alloc((size_t)E3 * Ee * 2);
  bf16_t* win   = (bf16_t*)alloc((size_t)E3 * Ee * 2);
  bf16_t* wout  = (bf16_t*)alloc((size_t)Ee * Ee * 2);
  bf16_t* wfin  = (bf16_t*)alloc((size_t)Ee * Ee * 2);
  bf16_t* woutT = (bf16_t*)alloc((size_t)Ee * Ee * 2);
  bf16_t* Wc    = (bf16_t*)alloc((size_t)Ee * Ee * 2);
  bf16_t* QKVb  = (bf16_t*)alloc((size_t)Ntok * E3 * 2);
  bf16_t* Vt    = (bf16_t*)alloc((size_t)Bb * Hh * Dd * Ss * 2);
  bf16_t* ctx   = (bf16_t*)alloc((size_t)Ntok * Ee * 2);
  bf16_t* qkv2  = (bf16_t*)alloc((size_t)Ntok * E3 * 2);
  bf16_t* v2t   = (bf16_t*)alloc((size_t)Bb * Hh * Dd * Ss * 2);
  bf16_t* ctx2  = (bf16_t*)alloc((size_t)Ntok * Ee * 2);
  float* part   = (float*)alloc((size_t)32 * 4 * 1024 * 4);
  float* xmean  = (float*)alloc(4096 * 4);
  float* hb     = (float*)alloc(4096 * 4);
  float* phase  = (float*)alloc(128 * 4);
  float* qkvb   = (float*)alloc(3072 * 4);
  float* bias_c = (float*)alloc(1024 * 4);

  hipFuncSetAttribute((const void*)attn_fused<1>,
                      hipFuncAttributeMaxDynamicSharedMemorySize, ATTN_LDS);
  hipFuncSetAttribute((const void*)attn_fused<0>,
                      hipFuncAttributeMaxDynamicSharedMemorySize, ATTN_LDS);
  hipFuncSetAttribute((const void*)gemm256<4>,
                      hipFuncAttributeMaxDynamicSharedMemorySize, G256_LDS);
  hipFuncSetAttribute((const void*)gemm256<0>,
                      hipFuncAttributeMaxDynamicSharedMemorySize, G256_LDS);

  // --- conversions + small prep
  conv_all<<<12288, 256, 0, stream>>>(x, q_w, k_w, v_w, in_w, out_w, fin_w,
                                      x_bf, wqkv, wqkv + (size_t)Ee * Ee,
                                      wqkv + (size_t)2 * Ee * Ee, win, wout, wfin);
  prepb<<<12, 256, 0, stream>>>(q_b, k_b, v_b, qkvb);
  biasck<<<16, 256, 0, stream>>>(fin_w, out_b, fin_b, bias_c);

  // --- phase chain (fp32)
  colmean_part<<<dim3(32, 4), 256, 0, stream>>>(x, part);
  colmean_fin<<<16, 256, 0, stream>>>(part, xmean);
  hgemm<<<16, 256, 0, stream>>>(xmean, ph_w1, ph_b1, hb);
  phasek<<<1, 128, 0, stream>>>(hb, ph_w2, ph_b2, phase);

  // --- Wc = fin_w @ out_w
  transpose1024<<<dim3(16, 16), 256, 0, stream>>>(wout, woutT);
  gemm_bt<0><<<dim3(8, 8), 256, 0, stream>>>(wfin, nullptr, woutT, nullptr, nullptr,
                                             Wc, 1024, Ee, Ee, Ee);

  // --- fused QKV projection (256^2 8-phase, phase fused on Q,K cols)
  gemm256<4><<<dim3(12, 16), 512, G256_LDS, stream>>>(x_bf, wqkv, qkvb, QKVb, phase,
                                                      Ee, Ee, E3);
  transpose_v<<<dim3(8, 128), 256, 0, stream>>>(QKVb + 2048, E3, Vt);

  // --- attention 1 (P -> d_out + fused PV)
  attn_fused<1><<<dim3(8, 128), 512, ATTN_LDS, stream>>>(QKVb, QKVb + 1024, E3, Vt,
                                                         attn_out, ctx, SCALE2);

  // --- MHA on context (in_proj 256^2 8-phase)
  gemm256<0><<<dim3(12, 16), 512, G256_LDS, stream>>>(ctx, win, in_b, qkv2, nullptr,
                                                      Ee, Ee, E3);
  transpose_v<<<dim3(8, 128), 256, 0, stream>>>(qkv2 + 2048, E3, v2t);
  attn_fused<0><<<dim3(8, 128), 512, ATTN_LDS, stream>>>(qkv2, qkv2 + 1024, E3, v2t,
                                                         nullptr, ctx2, SCALE2);

  // --- fused out_proj+residual+final: outp = ctx2@Wc^T + ctx@fin_w^T + bias_c
  gemm_bt<5><<<dim3(8, 32), 256, 0, stream>>>(ctx2, ctx, Wc, wfin, bias_c,
                                              outp, 2048, Ee, Ee, Ee);
}

// Round 8
// 514.072 us; speedup vs baseline: 1.0233x; 1.0233x over previous
//
#include <hip/hip_runtime.h>
#include <hip/hip_bf16.h>
#include <cstdint>
#include <cstddef>

typedef __bf16 bf16_t;
typedef __bf16 bf16x8 __attribute__((ext_vector_type(8)));
typedef __bf16 bf16x4 __attribute__((ext_vector_type(4)));
typedef float  f32x4  __attribute__((ext_vector_type(4)));

static constexpr int Bb = 4, Ss = 1024, Ee = 1024, Hh = 32, Dd = 32;
static constexpr int Ntok = Bb * Ss;   // 4096
static constexpr int E3   = 3 * Ee;    // 3072
static constexpr float SCALE2 = 0.25506060570135506f;   // (1/sqrt(32)) * log2(e)

__device__ __forceinline__ void gl_lds16(const void* g, void* l) {
  __builtin_amdgcn_global_load_lds(
      (const __attribute__((address_space(1))) void*)g,
      (__attribute__((address_space(3))) void*)l, 16, 0, 0);
}
__device__ __forceinline__ float fexp2(float x) { return __builtin_amdgcn_exp2f(x); }

// ---------------------------------------------------------------- fused f32->bf16 conversions
__global__ __launch_bounds__(256) void conv_all(const float* __restrict__ x,  const float* __restrict__ qw,
                                                const float* __restrict__ kw, const float* __restrict__ vw,
                                                const float* __restrict__ inw,const float* __restrict__ ow,
                                                const float* __restrict__ fw,
                                                bf16_t* xb, bf16_t* qb, bf16_t* kb, bf16_t* vb,
                                                bf16_t* inb, bf16_t* ob, bf16_t* fb) {
  const int i = blockIdx.x * 256 + threadIdx.x;
  const float* src; bf16_t* dst; int base;
  if      (i < 1048576) { src = x;   dst = xb;  base = 0; }
  else if (i < 1310720) { src = qw;  dst = qb;  base = 1048576; }
  else if (i < 1572864) { src = kw;  dst = kb;  base = 1310720; }
  else if (i < 1835008) { src = vw;  dst = vb;  base = 1572864; }
  else if (i < 2621440) { src = inw; dst = inb; base = 1835008; }
  else if (i < 2883584) { src = ow;  dst = ob;  base = 2621440; }
  else                  { src = fw;  dst = fb;  base = 2883584; }
  const int j = i - base;
  const float4 v = *(const float4*)(src + (size_t)j * 4);
  bf16x4 o = {(bf16_t)v.x, (bf16_t)v.y, (bf16_t)v.z, (bf16_t)v.w};
  *(bf16x4*)(dst + (size_t)j * 4) = o;
}

// ---------------------------------------------------------------- bias concat q_b|k_b|v_b
__global__ __launch_bounds__(256) void prepb(const float* __restrict__ qb, const float* __restrict__ kb,
                                             const float* __restrict__ vb, float* __restrict__ o) {
  const int i = blockIdx.x * 256 + threadIdx.x;
  o[i] = (i < 1024) ? qb[i] : (i < 2048) ? kb[i - 1024] : vb[i - 2048];
}

// ---------------------------------------------------------------- bias_c[n] = fin_b[n] + sum_j fin_w[n][j]*out_b[j]
// 64 blocks x 16 n each; 16 threads per n.
__global__ __launch_bounds__(256) void biasck(const float* __restrict__ fw, const float* __restrict__ ob,
                                              const float* __restrict__ fb, float* __restrict__ bc) {
  const int t = threadIdx.x;
  const int n = blockIdx.x * 16 + (t >> 4), p = t & 15;
  const float* row = fw + (size_t)n * 1024 + p * 64;
  const float* obp = ob + p * 64;
  float s = 0.f;
  for (int j = 0; j < 64; ++j) s += row[j] * obp[j];
  s += __shfl_xor(s, 1);
  s += __shfl_xor(s, 2);
  s += __shfl_xor(s, 4);
  s += __shfl_xor(s, 8);
  if (p == 0) bc[n] = s + fb[n];
}

// ---------------------------------------------------------------- mean over S
__global__ __launch_bounds__(256) void colmean_part(const float* __restrict__ x,
                                                    float* __restrict__ part) {
  const int b = blockIdx.y, sc = blockIdx.x;
  const float* base = x + ((size_t)b * Ss + sc * 32) * Ee;
  for (int k = 0; k < 4; ++k) {
    const int e = threadIdx.x + k * 256;
    float s = 0.f;
    for (int i = 0; i < 32; ++i) s += base[(size_t)i * Ee + e];
    part[((size_t)sc * 4 + b) * Ee + e] = s;
  }
}
__global__ __launch_bounds__(256) void colmean_fin(const float* __restrict__ part,
                                                   float* __restrict__ xm) {
  const int idx = blockIdx.x * 256 + threadIdx.x;
  const int b = idx >> 10, e = idx & 1023;
  float s = 0.f;
  for (int sc = 0; sc < 32; ++sc) s += part[((size_t)sc * 4 + b) * Ee + e];
  xm[idx] = s * (1.0f / 1024.0f);
}

// ---------------------------------------------------------------- h = relu(xmean @ w1^T + b1)
// 64 blocks x 16 j each; 16 threads per j (p = t&15 covers e-range p*64..p*64+63).
__global__ __launch_bounds__(256) void hgemm(const float* __restrict__ xm,
                                             const float* __restrict__ w1,
                                             const float* __restrict__ b1,
                                             float* __restrict__ hout) {
  __shared__ float xl[4 * 1024];
  for (int i = threadIdx.x; i < 4096; i += 256) xl[i] = xm[i];
  __syncthreads();
  const int j = blockIdx.x * 16 + (threadIdx.x >> 4);
  const int p = threadIdx.x & 15;
  const float* wr = w1 + (size_t)j * Ee + p * 64;
  float a0 = 0.f, a1 = 0.f, a2 = 0.f, a3 = 0.f;
  const int e0 = p * 64;
#pragma unroll 8
  for (int e = 0; e < 64; ++e) {
    const float wv = wr[e];
    a0 += xl[e0 + e] * wv;
    a1 += xl[1024 + e0 + e] * wv;
    a2 += xl[2048 + e0 + e] * wv;
    a3 += xl[3072 + e0 + e] * wv;
  }
#pragma unroll
  for (int m = 1; m <= 8; m <<= 1) {
    a0 += __shfl_xor(a0, m);
    a1 += __shfl_xor(a1, m);
    a2 += __shfl_xor(a2, m);
    a3 += __shfl_xor(a3, m);
  }
  if (p == 0) {
    const float bb = b1[j];
    hout[j]        = fmaxf(a0 + bb, 0.f);
    hout[1024 + j] = fmaxf(a1 + bb, 0.f);
    hout[2048 + j] = fmaxf(a2 + bb, 0.f);
    hout[3072 + j] = fmaxf(a3 + bb, 0.f);
  }
}

// ---------------------------------------------------------------- phase = cos(h @ w2^T + b2)
__global__ __launch_bounds__(128) void phasek(const float* __restrict__ hin,
                                              const float* __restrict__ w2,
                                              const float* __restrict__ b2,
                                              float* __restrict__ ph) {
  const int t = threadIdx.x;
  const int b = t >> 5, hh = t & 31;
  const float* hr = hin + b * 1024;
  const float* wr = w2 + (size_t)hh * Ee;
  float s = 0.f;
  for (int j = 0; j < 1024; ++j) s += hr[j] * wr[j];
  ph[t] = cosf(s + b2[hh]);
}

// ---------------------------------------------------------------- bf16 1024x1024 transpose
__global__ __launch_bounds__(256) void transpose1024(const bf16_t* __restrict__ in,
                                                     bf16_t* __restrict__ out) {
  __shared__ bf16_t t[64][72];
  const int jt = threadIdx.x >> 2, k16 = (threadIdx.x & 3) * 16;
  const int r0 = blockIdx.y * 64, c0 = blockIdx.x * 64;
  const bf16x8 a = *(const bf16x8*)(in + (size_t)(r0 + jt) * 1024 + c0 + k16);
  const bf16x8 b = *(const bf16x8*)(in + (size_t)(r0 + jt) * 1024 + c0 + k16 + 8);
  *(bf16x8*)&t[jt][k16] = a;
  *(bf16x8*)&t[jt][k16 + 8] = b;
  __syncthreads();
  bf16x8 v0, v1;
#pragma unroll
  for (int m = 0; m < 8; ++m) v0[m] = t[k16 + m][jt];
#pragma unroll
  for (int m = 0; m < 8; ++m) v1[m] = t[k16 + 8 + m][jt];
  *(bf16x8*)(out + (size_t)(c0 + jt) * 1024 + r0 + k16) = v0;
  *(bf16x8*)(out + (size_t)(c0 + jt) * 1024 + r0 + k16 + 8) = v1;
}

// ---------------------------------------------------------------- GEMM: C = A @ Bt^T + bias (+epilogue)
// MODE 0: bf16 | 4: bf16 * phase (3072-wide C, cols<2048) | 5: fp32 nt, split-K (A2/Bt2 for k>=1024)
template <int MODE>
__global__ __launch_bounds__(256) void gemm_bt(const bf16_t* __restrict__ A,
                                               const bf16_t* __restrict__ A2,
                                               const bf16_t* __restrict__ Bt,
                                               const bf16_t* __restrict__ Bt2,
                                               const float* __restrict__ bias,
                                               void* __restrict__ Cout,
                                               const float* __restrict__ phase,
                                               int K, int lda, int ldb, int ldc) {
  __shared__ bf16_t As[128 * 32];
  __shared__ bf16_t Bs[128 * 32];
  const int tid = threadIdx.x;
  const int w = tid >> 6, lane = tid & 63;
  const int nwg = gridDim.x * gridDim.y;     // always % 8 == 0 here
  int flat = blockIdx.y * gridDim.x + blockIdx.x;
  flat = (flat & 7) * (nwg >> 3) + (flat >> 3);
  const int m0 = (flat / gridDim.x) * 128, n0 = (flat % gridDim.x) * 128;
  const int wr = (w >> 1) * 64, wc = (w & 1) * 64;
  const int r_ld = lane >> 2, c_ld = (lane & 3) * 8;
  const int rr = lane & 15, kk8 = (lane >> 4) * 8;
  f32x4 acc[4][4];
#pragma unroll
  for (int m = 0; m < 4; ++m)
#pragma unroll
    for (int n = 0; n < 4; ++n) acc[m][n] = f32x4{0.f, 0.f, 0.f, 0.f};

  for (int kt = 0; kt < K; kt += 32) {
    const bf16_t* Ak = A;
    const bf16_t* Bk = Bt;
    int kk = kt;
    if constexpr (MODE == 5) {
      if (kt >= 1024) { Ak = A2; Bk = Bt2; kk = kt - 1024; }
    }
#pragma unroll
    for (int j = 0; j < 2; ++j) {
      const int r0 = w * 16 + j * 64;
      gl_lds16(Ak + (size_t)(m0 + r0 + r_ld) * lda + kk + c_ld, &As[r0 * 32]);
      gl_lds16(Bk + (size_t)(n0 + r0 + r_ld) * ldb + kk + c_ld, &Bs[r0 * 32]);
    }
    __syncthreads();
    bf16x8 af[4], bfr[4];
#pragma unroll
    for (int m = 0; m < 4; ++m) af[m] = *(const bf16x8*)&As[(wr + m * 16 + rr) * 32 + kk8];
#pragma unroll
    for (int n = 0; n < 4; ++n) bfr[n] = *(const bf16x8*)&Bs[(wc + n * 16 + rr) * 32 + kk8];
#pragma unroll
    for (int m = 0; m < 4; ++m)
#pragma unroll
      for (int n = 0; n < 4; ++n)
        acc[m][n] = __builtin_amdgcn_mfma_f32_16x16x32_bf16(af[m], bfr[n], acc[m][n], 0, 0, 0);
    __syncthreads();
  }

  const int rr4 = (lane >> 4) * 4, cc = lane & 15;
#pragma unroll
  for (int m = 0; m < 4; ++m) {
#pragma unroll
    for (int n = 0; n < 4; ++n) {
      const int gr0 = m0 + wr + m * 16 + rr4;
      const int gc = n0 + wc + n * 16 + cc;
      const float bb = bias ? bias[gc] : 0.f;
#pragma unroll
      for (int i = 0; i < 4; ++i) {
        const size_t idx = (size_t)(gr0 + i) * ldc + gc;
        float v = acc[m][n][i] + bb;
        if constexpr (MODE == 4) {
          if (gc < 2048) v *= phase[(((gr0 + i) >> 10) << 5) + ((gc >> 5) & 31)];
        }
        if constexpr (MODE == 5) __builtin_nontemporal_store(v, (float*)Cout + idx);
        else ((bf16_t*)Cout)[idx] = (bf16_t)v;
      }
    }
  }
}

// ---------------------------------------------------------------- V transpose: [token, e] -> [bh][d][s]
__global__ __launch_bounds__(256) void transpose_v(const bf16_t* __restrict__ src, int rs,
                                                   bf16_t* __restrict__ dst) {
  __shared__ bf16_t buf[128 * 33];
  const int bh = blockIdx.y, b = bh >> 5, h = bh & 31;
  const int s0 = blockIdx.x * 128;
  const bf16_t* in = src + ((size_t)b * Ss + s0) * rs + h * 32;
  for (int e = threadIdx.x; e < 128 * 32; e += 256) {
    const int s = e >> 5, d = e & 31;
    buf[s * 33 + d] = in[(size_t)s * rs + d];
  }
  __syncthreads();
  bf16_t* out = dst + (size_t)bh * (Dd * Ss) + s0;
  for (int e = threadIdx.x; e < 128 * 32; e += 256) {
    const int d = e >> 7, s = e & 127;
    out[(size_t)d * Ss + s] = buf[s * 33 + d];
  }
}

// ---------------------------------------------------------------- fused attention (R6 structure, nt P store)
static constexpr int K_PLANE_B = 16400;           // 1025*16 B per k-plane
static constexpr int V_OFF_B   = 4 * K_PLANE_B;   // 65600
static constexpr int V_ROW_B   = 2064;            // 1032 bf16
static constexpr int P_OFF_B   = V_OFF_B + 32 * V_ROW_B;  // 131648
static constexpr int P_WAVE_B  = 2304;            // 16 rows * 144 B
static constexpr int ATTN_LDS  = P_OFF_B + 8 * P_WAVE_B;  // 150080

template <int WRITE_P>
__global__ __launch_bounds__(512) void attn_fused(const bf16_t* __restrict__ Qm,
                                                  const bf16_t* __restrict__ Km, int rs,
                                                  const bf16_t* __restrict__ Vt,
                                                  float* __restrict__ Pout,
                                                  bf16_t* __restrict__ ctx, float scale2) {
  extern __shared__ char smem[];
  char* Kl = smem;
  char* Vl = smem + V_OFF_B;
  const int tid = threadIdx.x, lane = tid & 63, w = tid >> 6;
  const int g = lane >> 4, r = lane & 15;
  int flat = blockIdx.y * 8 + blockIdx.x;
  flat = (flat & 7) * 128 + (flat >> 3);             // XCD: blocks of one bh co-XCD
  const int bh = flat >> 3, xb = flat & 7;
  const int b = bh >> 5, h = bh & 31;
  char* myP = smem + P_OFF_B + w * P_WAVE_B;

  // stage K: wave w -> plane pg=w>>1, half hh=w&1
  {
    const bf16_t* Kbase = Km + (size_t)b * Ss * rs + h * 32;
    const int pg = w >> 1, hh = w & 1;
#pragma unroll
    for (int c = 0; c < 8; ++c) {
      const int row0 = hh * 512 + c * 64;
      gl_lds16(Kbase + (size_t)(row0 + lane) * rs + pg * 8, Kl + pg * K_PLANE_B + row0 * 16);
    }
  }
  // stage V: wave w -> d-rows 4w..4w+3
  {
    const bf16_t* vsrc = Vt + (size_t)bh * (Dd * Ss);
#pragma unroll
    for (int rr2 = 0; rr2 < 4; ++rr2) {
      const int row = w * 4 + rr2;
#pragma unroll
      for (int c = 0; c < 2; ++c)
        gl_lds16(vsrc + (size_t)row * Ss + c * 512 + lane * 8, Vl + row * V_ROW_B + c * 1024);
    }
  }
  const int qrow0 = xb * 128 + w * 16;
  const bf16x8 qraw = *(const bf16x8*)(Qm + ((size_t)b * Ss + qrow0 + r) * rs + h * 32 + g * 8);
  bf16x8 qf;  // pre-scaled by SCALE*log2e -> raw v_exp
#pragma unroll
  for (int i = 0; i < 8; ++i) qf[i] = (bf16_t)((float)qraw[i] * scale2);
  __syncthreads();

  const f32x4 zero = {0.f, 0.f, 0.f, 0.f};
  float lsum = 0.f, rinv = 1.f;

  if constexpr (WRITE_P) {
    // pass 1: row sums
    for (int kt = 0; kt < 16; ++kt) {
#pragma unroll
      for (int n = 0; n < 4; ++n) {
        const int key = kt * 64 + n * 16 + r;
        const bf16x8 kf = *(const bf16x8*)(Kl + g * K_PLANE_B + key * 16);
        const f32x4 s = __builtin_amdgcn_mfma_f32_16x16x32_bf16(kf, qf, zero, 0, 0, 0);
#pragma unroll
        for (int i = 0; i < 4; ++i) lsum += fexp2(s[i]);
      }
    }
    lsum += __shfl_xor(lsum, 16);
    lsum += __shfl_xor(lsum, 32);
    rinv = 1.0f / lsum;
  }

  f32x4 acc2[2] = {zero, zero};  // acc2[dn][i] = ctx[q=qrow0+r][d=dn*16+4g+i]
  const size_t pbase = (size_t)bh * Ss * Ss;

  for (int kt = 0; kt < 16; ++kt) {
    float p[4][4];
#pragma unroll
    for (int n = 0; n < 4; ++n) {
      const int key = kt * 64 + n * 16 + r;
      const bf16x8 kf = *(const bf16x8*)(Kl + g * K_PLANE_B + key * 16);
      const f32x4 s = __builtin_amdgcn_mfma_f32_16x16x32_bf16(kf, qf, zero, 0, 0, 0);
#pragma unroll
      for (int i = 0; i < 4; ++i) {
        float e = fexp2(s[i]);
        if constexpr (WRITE_P) e *= rinv;
        else lsum += e;
        p[n][i] = e;
      }
      bf16x4 pw = {(bf16_t)p[n][0], (bf16_t)p[n][1], (bf16_t)p[n][2], (bf16_t)p[n][3]};
      *(bf16x4*)(myP + r * 144 + (n * 16 + g * 4) * 2) = pw;
      if constexpr (WRITE_P) {
        f32x4 w4 = {p[n][0], p[n][1], p[n][2], p[n][3]};
        __builtin_nontemporal_store(
            w4, (f32x4*)&Pout[pbase + (size_t)(qrow0 + r) * Ss + kt * 64 + n * 16 + 4 * g]);
      }
    }
    // PV: A = V^T d-rows, B = P^T
#pragma unroll
    for (int c = 0; c < 2; ++c) {
      const bf16x8 pa = *(const bf16x8*)(myP + r * 144 + (c * 32 + 8 * g) * 2);
#pragma unroll
      for (int dn = 0; dn < 2; ++dn) {
        const bf16x8 vf = *(const bf16x8*)(Vl + (dn * 16 + r) * V_ROW_B +
                                           (kt * 64 + c * 32 + g * 8) * 2);
        acc2[dn] = __builtin_amdgcn_mfma_f32_16x16x32_bf16(vf, pa, acc2[dn], 0, 0, 0);
      }
    }
  }

  if constexpr (!WRITE_P) {
    lsum += __shfl_xor(lsum, 16);
    lsum += __shfl_xor(lsum, 32);
    rinv = 1.0f / lsum;
#pragma unroll
    for (int dn = 0; dn < 2; ++dn)
#pragma unroll
      for (int i = 0; i < 4; ++i) acc2[dn][i] *= rinv;
  }

  // ctx^T -> ctx via per-wave LDS transpose (reuse myP as float tile [16][36])
  float* Ct = (float*)myP;
#pragma unroll
  for (int dn = 0; dn < 2; ++dn)
#pragma unroll
    for (int i = 0; i < 4; ++i)
      Ct[r * 36 + dn * 16 + 4 * g + i] = acc2[dn][i];
  const int q2 = lane >> 2, pt = lane & 3;
  const f32x4 ca = *(const f32x4*)(myP + q2 * 144 + pt * 32);
  const f32x4 cb = *(const f32x4*)(myP + q2 * 144 + pt * 32 + 16);
  bf16x8 cv = {(bf16_t)ca[0], (bf16_t)ca[1], (bf16_t)ca[2], (bf16_t)ca[3],
               (bf16_t)cb[0], (bf16_t)cb[1], (bf16_t)cb[2], (bf16_t)cb[3]};
  *(bf16x8*)&ctx[((size_t)b * Ss + qrow0 + q2) * Ee + h * 32 + pt * 8] = cv;
}

// ================================================================ launcher
extern "C" void kernel_launch(void* const* d_in, const int* in_sizes, int n_in,
                              void* d_out, int out_size, void* d_ws, size_t ws_size,
                              hipStream_t stream) {
  const float* x     = (const float*)d_in[0];
  const float* q_w   = (const float*)d_in[1];
  const float* q_b   = (const float*)d_in[2];
  const float* k_w   = (const float*)d_in[3];
  const float* k_b   = (const float*)d_in[4];
  const float* v_w   = (const float*)d_in[5];
  const float* v_b   = (const float*)d_in[6];
  const float* ph_w1 = (const float*)d_in[7];
  const float* ph_b1 = (const float*)d_in[8];
  const float* ph_w2 = (const float*)d_in[9];
  const float* ph_b2 = (const float*)d_in[10];
  const float* in_w  = (const float*)d_in[11];
  const float* in_b  = (const float*)d_in[12];
  const float* out_w = (const float*)d_in[13];
  const float* out_b = (const float*)d_in[14];
  const float* fin_w = (const float*)d_in[15];
  const float* fin_b = (const float*)d_in[16];

  float* outp = (float*)d_out;
  float* attn_out = outp + (size_t)Ntok * Ee;

  char* ws = (char*)d_ws;
  size_t off = 0;
  auto alloc = [&](size_t bytes) -> void* {
    void* p = ws + off;
    off += (bytes + 255) & ~(size_t)255;
    return p;
  };
  bf16_t* x_bf  = (bf16_t*)alloc((size_t)Ntok * Ee * 2);
  bf16_t* wqkv  = (bf16_t*)alloc((size_t)E3 * Ee * 2);
  bf16_t* win   = (bf16_t*)alloc((size_t)E3 * Ee * 2);
  bf16_t* wout  = (bf16_t*)alloc((size_t)Ee * Ee * 2);
  bf16_t* wfin  = (bf16_t*)alloc((size_t)Ee * Ee * 2);
  bf16_t* woutT = (bf16_t*)alloc((size_t)Ee * Ee * 2);
  bf16_t* Wc    = (bf16_t*)alloc((size_t)Ee * Ee * 2);
  bf16_t* QKVb  = (bf16_t*)alloc((size_t)Ntok * E3 * 2);
  bf16_t* Vt    = (bf16_t*)alloc((size_t)Bb * Hh * Dd * Ss * 2);
  bf16_t* ctx   = (bf16_t*)alloc((size_t)Ntok * Ee * 2);
  bf16_t* qkv2  = (bf16_t*)alloc((size_t)Ntok * E3 * 2);
  bf16_t* v2t   = (bf16_t*)alloc((size_t)Bb * Hh * Dd * Ss * 2);
  bf16_t* ctx2  = (bf16_t*)alloc((size_t)Ntok * Ee * 2);
  float* part   = (float*)alloc((size_t)32 * 4 * 1024 * 4);
  float* xmean  = (float*)alloc(4096 * 4);
  float* hb     = (float*)alloc(4096 * 4);
  float* phase  = (float*)alloc(128 * 4);
  float* qkvb   = (float*)alloc(3072 * 4);
  float* bias_c = (float*)alloc(1024 * 4);

  hipFuncSetAttribute((const void*)attn_fused<1>,
                      hipFuncAttributeMaxDynamicSharedMemorySize, ATTN_LDS);
  hipFuncSetAttribute((const void*)attn_fused<0>,
                      hipFuncAttributeMaxDynamicSharedMemorySize, ATTN_LDS);

  // --- conversions + small prep (all wide)
  conv_all<<<12288, 256, 0, stream>>>(x, q_w, k_w, v_w, in_w, out_w, fin_w,
                                      x_bf, wqkv, wqkv + (size_t)Ee * Ee,
                                      wqkv + (size_t)2 * Ee * Ee, win, wout, wfin);
  prepb<<<12, 256, 0, stream>>>(q_b, k_b, v_b, qkvb);
  biasck<<<64, 256, 0, stream>>>(fin_w, out_b, fin_b, bias_c);

  // --- phase chain (fp32)
  colmean_part<<<dim3(32, 4), 256, 0, stream>>>(x, part);
  colmean_fin<<<16, 256, 0, stream>>>(part, xmean);
  hgemm<<<64, 256, 0, stream>>>(xmean, ph_w1, ph_b1, hb);
  phasek<<<1, 128, 0, stream>>>(hb, ph_w2, ph_b2, phase);

  // --- Wc = fin_w @ out_w (for out_proj+final fusion)
  transpose1024<<<dim3(16, 16), 256, 0, stream>>>(wout, woutT);
  gemm_bt<0><<<dim3(8, 8), 256, 0, stream>>>(wfin, nullptr, woutT, nullptr, nullptr,
                                             Wc, nullptr, 1024, Ee, Ee, Ee);

  // --- fused QKV projection (phase applied to Q,K cols in epilogue)
  gemm_bt<4><<<dim3(24, 32), 256, 0, stream>>>(x_bf, nullptr, wqkv, nullptr, qkvb,
                                               QKVb, phase, 1024, Ee, Ee, E3);
  transpose_v<<<dim3(8, 128), 256, 0, stream>>>(QKVb + 2048, E3, Vt);

  // --- attention 1 (P -> d_out + fused PV)
  attn_fused<1><<<dim3(8, 128), 512, ATTN_LDS, stream>>>(QKVb, QKVb + 1024, E3, Vt,
                                                         attn_out, ctx, SCALE2);

  // --- MHA on context
  gemm_bt<0><<<dim3(24, 32), 256, 0, stream>>>(ctx, nullptr, win, nullptr, in_b,
                                               qkv2, nullptr, 1024, Ee, Ee, E3);
  transpose_v<<<dim3(8, 128), 256, 0, stream>>>(qkv2 + 2048, E3, v2t);
  attn_fused<0><<<dim3(8, 128), 512, ATTN_LDS, stream>>>(qkv2, qkv2 + 1024, E3, v2t,
                                                         nullptr, ctx2, SCALE2);

  // --- fused out_proj+residual+final: outp = ctx2@Wc^T + ctx@fin_w^T + bias_c
  gemm_bt<5><<<dim3(8, 32), 256, 0, stream>>>(ctx2, ctx, Wc, wfin, bias_c,
                                              outp, nullptr, 2048, Ee, Ee, Ee);
}

// Round 9
// 498.413 us; speedup vs baseline: 1.0554x; 1.0314x over previous
//
#include <hip/hip_runtime.h>
#include <hip/hip_bf16.h>
#include <cstdint>
#include <cstddef>

typedef __bf16 bf16_t;
typedef __bf16 bf16x8 __attribute__((ext_vector_type(8)));
typedef __bf16 bf16x4 __attribute__((ext_vector_type(4)));
typedef float  f32x4  __attribute__((ext_vector_type(4)));

static constexpr int Bb = 4, Ss = 1024, Ee = 1024, Hh = 32, Dd = 32;
static constexpr int Ntok = Bb * Ss;   // 4096
static constexpr int E3   = 3 * Ee;    // 3072
static constexpr float SCALE2 = 0.25506060570135506f;   // (1/sqrt(32)) * log2(e)

__device__ __forceinline__ void gl_lds16(const void* g, void* l) {
  __builtin_amdgcn_global_load_lds(
      (const __attribute__((address_space(1))) void*)g,
      (__attribute__((address_space(3))) void*)l, 16, 0, 0);
}
__device__ __forceinline__ float fexp2(float x) { return __builtin_amdgcn_exp2f(x); }

// ---------------------------------------------------------------- fused f32->bf16 conversions
__global__ __launch_bounds__(256) void conv_all(const float* __restrict__ x,  const float* __restrict__ qw,
                                                const float* __restrict__ kw, const float* __restrict__ vw,
                                                const float* __restrict__ inw,const float* __restrict__ ow,
                                                const float* __restrict__ fw,
                                                bf16_t* xb, bf16_t* qb, bf16_t* kb, bf16_t* vb,
                                                bf16_t* inb, bf16_t* ob, bf16_t* fb) {
  const int i = blockIdx.x * 256 + threadIdx.x;
  const float* src; bf16_t* dst; int base;
  if      (i < 1048576) { src = x;   dst = xb;  base = 0; }
  else if (i < 1310720) { src = qw;  dst = qb;  base = 1048576; }
  else if (i < 1572864) { src = kw;  dst = kb;  base = 1310720; }
  else if (i < 1835008) { src = vw;  dst = vb;  base = 1572864; }
  else if (i < 2621440) { src = inw; dst = inb; base = 1835008; }
  else if (i < 2883584) { src = ow;  dst = ob;  base = 2621440; }
  else                  { src = fw;  dst = fb;  base = 2883584; }
  const int j = i - base;
  const float4 v = *(const float4*)(src + (size_t)j * 4);
  bf16x4 o = {(bf16_t)v.x, (bf16_t)v.y, (bf16_t)v.z, (bf16_t)v.w};
  *(bf16x4*)(dst + (size_t)j * 4) = o;
}

// ---------------------------------------------------------------- bias_c (blocks 0..63) + qkv bias concat (64..75)
__global__ __launch_bounds__(256) void biasck(const float* __restrict__ fw, const float* __restrict__ ob,
                                              const float* __restrict__ fb, float* __restrict__ bc,
                                              const float* __restrict__ qb, const float* __restrict__ kb,
                                              const float* __restrict__ vb, float* __restrict__ qkvb) {
  const int t = threadIdx.x;
  if (blockIdx.x >= 64) {
    const int i = (blockIdx.x - 64) * 256 + t;
    qkvb[i] = (i < 1024) ? qb[i] : (i < 2048) ? kb[i - 1024] : vb[i - 2048];
    return;
  }
  const int n = blockIdx.x * 16 + (t >> 4), p = t & 15;
  const float* row = fw + (size_t)n * 1024 + p * 64;
  const float* obp = ob + p * 64;
  float s = 0.f;
  for (int j = 0; j < 64; ++j) s += row[j] * obp[j];
  s += __shfl_xor(s, 1);
  s += __shfl_xor(s, 2);
  s += __shfl_xor(s, 4);
  s += __shfl_xor(s, 8);
  if (p == 0) bc[n] = s + fb[n];
}

// ---------------------------------------------------------------- mean over S
__global__ __launch_bounds__(256) void colmean_part(const float* __restrict__ x,
                                                    float* __restrict__ part) {
  const int b = blockIdx.y, sc = blockIdx.x;
  const float* base = x + ((size_t)b * Ss + sc * 32) * Ee;
  for (int k = 0; k < 4; ++k) {
    const int e = threadIdx.x + k * 256;
    float s = 0.f;
    for (int i = 0; i < 32; ++i) s += base[(size_t)i * Ee + e];
    part[((size_t)sc * 4 + b) * Ee + e] = s;
  }
}
__global__ __launch_bounds__(256) void colmean_fin(const float* __restrict__ part,
                                                   float* __restrict__ xm) {
  const int idx = blockIdx.x * 256 + threadIdx.x;
  const int b = idx >> 10, e = idx & 1023;
  float s = 0.f;
  for (int sc = 0; sc < 32; ++sc) s += part[((size_t)sc * 4 + b) * Ee + e];
  xm[idx] = s * (1.0f / 1024.0f);
}

// ---------------------------------------------------------------- h = relu(xmean @ w1^T + b1), 64 blocks
__global__ __launch_bounds__(256) void hgemm(const float* __restrict__ xm,
                                             const float* __restrict__ w1,
                                             const float* __restrict__ b1,
                                             float* __restrict__ hout) {
  __shared__ float xl[4 * 1024];
  for (int i = threadIdx.x; i < 4096; i += 256) xl[i] = xm[i];
  __syncthreads();
  const int j = blockIdx.x * 16 + (threadIdx.x >> 4);
  const int p = threadIdx.x & 15;
  const float* wr = w1 + (size_t)j * Ee + p * 64;
  float a0 = 0.f, a1 = 0.f, a2 = 0.f, a3 = 0.f;
  const int e0 = p * 64;
#pragma unroll 8
  for (int e = 0; e < 64; ++e) {
    const float wv = wr[e];
    a0 += xl[e0 + e] * wv;
    a1 += xl[1024 + e0 + e] * wv;
    a2 += xl[2048 + e0 + e] * wv;
    a3 += xl[3072 + e0 + e] * wv;
  }
#pragma unroll
  for (int m = 1; m <= 8; m <<= 1) {
    a0 += __shfl_xor(a0, m);
    a1 += __shfl_xor(a1, m);
    a2 += __shfl_xor(a2, m);
    a3 += __shfl_xor(a3, m);
  }
  if (p == 0) {
    const float bb = b1[j];
    hout[j]        = fmaxf(a0 + bb, 0.f);
    hout[1024 + j] = fmaxf(a1 + bb, 0.f);
    hout[2048 + j] = fmaxf(a2 + bb, 0.f);
    hout[3072 + j] = fmaxf(a3 + bb, 0.f);
  }
}

// ---------------------------------------------------------------- phase = cos(h @ w2^T + b2)
__global__ __launch_bounds__(128) void phasek(const float* __restrict__ hin,
                                              const float* __restrict__ w2,
                                              const float* __restrict__ b2,
                                              float* __restrict__ ph) {
  const int t = threadIdx.x;
  const int b = t >> 5, hh = t & 31;
  const float* hr = hin + b * 1024;
  const float* wr = w2 + (size_t)hh * Ee;
  float s = 0.f;
  for (int j = 0; j < 1024; ++j) s += hr[j] * wr[j];
  ph[t] = cosf(s + b2[hh]);
}

// ---------------------------------------------------------------- bf16 1024x1024 transpose
__global__ __launch_bounds__(256) void transpose1024(const bf16_t* __restrict__ in,
                                                     bf16_t* __restrict__ out) {
  __shared__ bf16_t t[64][72];
  const int jt = threadIdx.x >> 2, k16 = (threadIdx.x & 3) * 16;
  const int r0 = blockIdx.y * 64, c0 = blockIdx.x * 64;
  const bf16x8 a = *(const bf16x8*)(in + (size_t)(r0 + jt) * 1024 + c0 + k16);
  const bf16x8 b = *(const bf16x8*)(in + (size_t)(r0 + jt) * 1024 + c0 + k16 + 8);
  *(bf16x8*)&t[jt][k16] = a;
  *(bf16x8*)&t[jt][k16 + 8] = b;
  __syncthreads();
  bf16x8 v0, v1;
#pragma unroll
  for (int m = 0; m < 8; ++m) v0[m] = t[k16 + m][jt];
#pragma unroll
  for (int m = 0; m < 8; ++m) v1[m] = t[k16 + 8 + m][jt];
  *(bf16x8*)(out + (size_t)(c0 + jt) * 1024 + r0 + k16) = v0;
  *(bf16x8*)(out + (size_t)(c0 + jt) * 1024 + r0 + k16 + 8) = v1;
}

// ---------------------------------------------------------------- GEMM 128x128: MODE 0 bf16 | 4 bf16*phase
template <int MODE>
__global__ __launch_bounds__(256) void gemm_bt(const bf16_t* __restrict__ A,
                                               const bf16_t* __restrict__ Bt,
                                               const float* __restrict__ bias,
                                               void* __restrict__ Cout,
                                               const float* __restrict__ phase,
                                               int K, int lda, int ldb, int ldc) {
  __shared__ bf16_t As[128 * 32];
  __shared__ bf16_t Bs[128 * 32];
  const int tid = threadIdx.x;
  const int w = tid >> 6, lane = tid & 63;
  const int nwg = gridDim.x * gridDim.y;     // always % 8 == 0 here
  int flat = blockIdx.y * gridDim.x + blockIdx.x;
  flat = (flat & 7) * (nwg >> 3) + (flat >> 3);
  const int m0 = (flat / gridDim.x) * 128, n0 = (flat % gridDim.x) * 128;
  const int wr = (w >> 1) * 64, wc = (w & 1) * 64;
  const int r_ld = lane >> 2, c_ld = (lane & 3) * 8;
  const int rr = lane & 15, kk8 = (lane >> 4) * 8;
  f32x4 acc[4][4];
#pragma unroll
  for (int m = 0; m < 4; ++m)
#pragma unroll
    for (int n = 0; n < 4; ++n) acc[m][n] = f32x4{0.f, 0.f, 0.f, 0.f};

  for (int kt = 0; kt < K; kt += 32) {
#pragma unroll
    for (int j = 0; j < 2; ++j) {
      const int r0 = w * 16 + j * 64;
      gl_lds16(A + (size_t)(m0 + r0 + r_ld) * lda + kt + c_ld, &As[r0 * 32]);
      gl_lds16(Bt + (size_t)(n0 + r0 + r_ld) * ldb + kt + c_ld, &Bs[r0 * 32]);
    }
    __syncthreads();
    bf16x8 af[4], bfr[4];
#pragma unroll
    for (int m = 0; m < 4; ++m) af[m] = *(const bf16x8*)&As[(wr + m * 16 + rr) * 32 + kk8];
#pragma unroll
    for (int n = 0; n < 4; ++n) bfr[n] = *(const bf16x8*)&Bs[(wc + n * 16 + rr) * 32 + kk8];
#pragma unroll
    for (int m = 0; m < 4; ++m)
#pragma unroll
      for (int n = 0; n < 4; ++n)
        acc[m][n] = __builtin_amdgcn_mfma_f32_16x16x32_bf16(af[m], bfr[n], acc[m][n], 0, 0, 0);
    __syncthreads();
  }

  const int rr4 = (lane >> 4) * 4, cc = lane & 15;
#pragma unroll
  for (int m = 0; m < 4; ++m) {
#pragma unroll
    for (int n = 0; n < 4; ++n) {
      const int gr0 = m0 + wr + m * 16 + rr4;
      const int gc = n0 + wc + n * 16 + cc;
      const float bb = bias ? bias[gc] : 0.f;
#pragma unroll
      for (int i = 0; i < 4; ++i) {
        const size_t idx = (size_t)(gr0 + i) * ldc + gc;
        float v = acc[m][n][i] + bb;
        if constexpr (MODE == 4) {
          if (gc < 2048) v *= phase[(((gr0 + i) >> 10) << 5) + ((gc >> 5) & 31)];
        }
        ((bf16_t*)Cout)[idx] = (bf16_t)v;
      }
    }
  }
}

// ---------------------------------------------------------------- GEMM 128x64 (grid-starved shapes)
// 4 waves, wave w owns rows w*32..w*32+31 x all 64 cols. MODE 0: bf16 | 5: fp32 nt, split-K at k=1024
template <int MODE>
__global__ __launch_bounds__(256) void gemm_n64(const bf16_t* __restrict__ A,
                                                const bf16_t* __restrict__ A2,
                                                const bf16_t* __restrict__ Bt,
                                                const bf16_t* __restrict__ Bt2,
                                                const float* __restrict__ bias,
                                                void* __restrict__ Cout,
                                                int K, int lda, int ldb, int ldc) {
  __shared__ bf16_t As[128 * 32];
  __shared__ bf16_t Bs[64 * 32];
  const int tid = threadIdx.x;
  const int w = tid >> 6, lane = tid & 63;
  const int nwg = gridDim.x * gridDim.y;   // % 8 == 0
  int flat = blockIdx.y * gridDim.x + blockIdx.x;
  flat = (flat & 7) * (nwg >> 3) + (flat >> 3);
  const int m0 = (flat / gridDim.x) * 128, n0 = (flat % gridDim.x) * 64;
  const int r_ld = lane >> 2, c_ld = (lane & 3) * 8;
  const int rr = lane & 15, kk8 = (lane >> 4) * 8;
  f32x4 acc[2][4];
#pragma unroll
  for (int m = 0; m < 2; ++m)
#pragma unroll
    for (int n = 0; n < 4; ++n) acc[m][n] = f32x4{0.f, 0.f, 0.f, 0.f};

  for (int kt = 0; kt < K; kt += 32) {
    const bf16_t* Ak = A;
    const bf16_t* Bk = Bt;
    int kk = kt;
    if constexpr (MODE == 5) {
      if (kt >= 1024) { Ak = A2; Bk = Bt2; kk = kt - 1024; }
    }
#pragma unroll
    for (int j = 0; j < 2; ++j) {
      const int r0 = w * 16 + j * 64;
      gl_lds16(Ak + (size_t)(m0 + r0 + r_ld) * lda + kk + c_ld, &As[r0 * 32]);
    }
    {
      const int r0 = w * 16;
      gl_lds16(Bk + (size_t)(n0 + r0 + r_ld) * ldb + kk + c_ld, &Bs[r0 * 32]);
    }
    __syncthreads();
    bf16x8 af[2], bfr[4];
#pragma unroll
    for (int m = 0; m < 2; ++m) af[m] = *(const bf16x8*)&As[(w * 32 + m * 16 + rr) * 32 + kk8];
#pragma unroll
    for (int n = 0; n < 4; ++n) bfr[n] = *(const bf16x8*)&Bs[(n * 16 + rr) * 32 + kk8];
#pragma unroll
    for (int m = 0; m < 2; ++m)
#pragma unroll
      for (int n = 0; n < 4; ++n)
        acc[m][n] = __builtin_amdgcn_mfma_f32_16x16x32_bf16(af[m], bfr[n], acc[m][n], 0, 0, 0);
    __syncthreads();
  }

  const int rr4 = (lane >> 4) * 4, cc = lane & 15;
#pragma unroll
  for (int m = 0; m < 2; ++m) {
#pragma unroll
    for (int n = 0; n < 4; ++n) {
      const int gr0 = m0 + w * 32 + m * 16 + rr4;
      const int gc = n0 + n * 16 + cc;
      const float bb = bias ? bias[gc] : 0.f;
#pragma unroll
      for (int i = 0; i < 4; ++i) {
        const size_t idx = (size_t)(gr0 + i) * ldc + gc;
        float v = acc[m][n][i] + bb;
        if constexpr (MODE == 5) __builtin_nontemporal_store(v, (float*)Cout + idx);
        else ((bf16_t*)Cout)[idx] = (bf16_t)v;
      }
    }
  }
}

// ---------------------------------------------------------------- V transpose: [token, e] -> [bh][d][s]
__global__ __launch_bounds__(256) void transpose_v(const bf16_t* __restrict__ src, int rs,
                                                   bf16_t* __restrict__ dst) {
  __shared__ bf16_t buf[128 * 33];
  const int bh = blockIdx.y, b = bh >> 5, h = bh & 31;
  const int s0 = blockIdx.x * 128;
  const bf16_t* in = src + ((size_t)b * Ss + s0) * rs + h * 32;
  for (int e = threadIdx.x; e < 128 * 32; e += 256) {
    const int s = e >> 5, d = e & 31;
    buf[s * 33 + d] = in[(size_t)s * rs + d];
  }
  __syncthreads();
  bf16_t* out = dst + (size_t)bh * (Dd * Ss) + s0;
  for (int e = threadIdx.x; e < 128 * 32; e += 256) {
    const int d = e >> 7, s = e & 127;
    out[(size_t)d * Ss + s] = buf[s * 33 + d];
  }
}

// ---------------------------------------------------------------- fused attention (R6 structure, nt P store)
static constexpr int K_PLANE_B = 16400;           // 1025*16 B per k-plane
static constexpr int V_OFF_B   = 4 * K_PLANE_B;   // 65600
static constexpr int V_ROW_B   = 2064;            // 1032 bf16
static constexpr int P_OFF_B   = V_OFF_B + 32 * V_ROW_B;  // 131648
static constexpr int P_WAVE_B  = 2304;            // 16 rows * 144 B
static constexpr int ATTN_LDS  = P_OFF_B + 8 * P_WAVE_B;  // 150080

template <int WRITE_P>
__global__ __launch_bounds__(512) void attn_fused(const bf16_t* __restrict__ Qm,
                                                  const bf16_t* __restrict__ Km, int rs,
                                                  const bf16_t* __restrict__ Vt,
                                                  float* __restrict__ Pout,
                                                  bf16_t* __restrict__ ctx, float scale2) {
  extern __shared__ char smem[];
  char* Kl = smem;
  char* Vl = smem + V_OFF_B;
  const int tid = threadIdx.x, lane = tid & 63, w = tid >> 6;
  const int g = lane >> 4, r = lane & 15;
  int flat = blockIdx.y * 8 + blockIdx.x;
  flat = (flat & 7) * 128 + (flat >> 3);             // XCD: blocks of one bh co-XCD
  const int bh = flat >> 3, xb = flat & 7;
  const int b = bh >> 5, h = bh & 31;
  char* myP = smem + P_OFF_B + w * P_WAVE_B;

  {
    const bf16_t* Kbase = Km + (size_t)b * Ss * rs + h * 32;
    const int pg = w >> 1, hh = w & 1;
#pragma unroll
    for (int c = 0; c < 8; ++c) {
      const int row0 = hh * 512 + c * 64;
      gl_lds16(Kbase + (size_t)(row0 + lane) * rs + pg * 8, Kl + pg * K_PLANE_B + row0 * 16);
    }
  }
  {
    const bf16_t* vsrc = Vt + (size_t)bh * (Dd * Ss);
#pragma unroll
    for (int rr2 = 0; rr2 < 4; ++rr2) {
      const int row = w * 4 + rr2;
#pragma unroll
      for (int c = 0; c < 2; ++c)
        gl_lds16(vsrc + (size_t)row * Ss + c * 512 + lane * 8, Vl + row * V_ROW_B + c * 1024);
    }
  }
  const int qrow0 = xb * 128 + w * 16;
  const bf16x8 qraw = *(const bf16x8*)(Qm + ((size_t)b * Ss + qrow0 + r) * rs + h * 32 + g * 8);
  bf16x8 qf;
#pragma unroll
  for (int i = 0; i < 8; ++i) qf[i] = (bf16_t)((float)qraw[i] * scale2);
  __syncthreads();

  const f32x4 zero = {0.f, 0.f, 0.f, 0.f};
  float lsum = 0.f, rinv = 1.f;

  if constexpr (WRITE_P) {
    for (int kt = 0; kt < 16; ++kt) {
#pragma unroll
      for (int n = 0; n < 4; ++n) {
        const int key = kt * 64 + n * 16 + r;
        const bf16x8 kf = *(const bf16x8*)(Kl + g * K_PLANE_B + key * 16);
        const f32x4 s = __builtin_amdgcn_mfma_f32_16x16x32_bf16(kf, qf, zero, 0, 0, 0);
#pragma unroll
        for (int i = 0; i < 4; ++i) lsum += fexp2(s[i]);
      }
    }
    lsum += __shfl_xor(lsum, 16);
    lsum += __shfl_xor(lsum, 32);
    rinv = 1.0f / lsum;
  }

  f32x4 acc2[2] = {zero, zero};
  const size_t pbase = (size_t)bh * Ss * Ss;

  for (int kt = 0; kt < 16; ++kt) {
    float p[4][4];
#pragma unroll
    for (int n = 0; n < 4; ++n) {
      const int key = kt * 64 + n * 16 + r;
      const bf16x8 kf = *(const bf16x8*)(Kl + g * K_PLANE_B + key * 16);
      const f32x4 s = __builtin_amdgcn_mfma_f32_16x16x32_bf16(kf, qf, zero, 0, 0, 0);
#pragma unroll
      for (int i = 0; i < 4; ++i) {
        float e = fexp2(s[i]);
        if constexpr (WRITE_P) e *= rinv;
        else lsum += e;
        p[n][i] = e;
      }
      bf16x4 pw = {(bf16_t)p[n][0], (bf16_t)p[n][1], (bf16_t)p[n][2], (bf16_t)p[n][3]};
      *(bf16x4*)(myP + r * 144 + (n * 16 + g * 4) * 2) = pw;
      if constexpr (WRITE_P) {
        f32x4 w4 = {p[n][0], p[n][1], p[n][2], p[n][3]};
        __builtin_nontemporal_store(
            w4, (f32x4*)&Pout[pbase + (size_t)(qrow0 + r) * Ss + kt * 64 + n * 16 + 4 * g]);
      }
    }
#pragma unroll
    for (int c = 0; c < 2; ++c) {
      const bf16x8 pa = *(const bf16x8*)(myP + r * 144 + (c * 32 + 8 * g) * 2);
#pragma unroll
      for (int dn = 0; dn < 2; ++dn) {
        const bf16x8 vf = *(const bf16x8*)(Vl + (dn * 16 + r) * V_ROW_B +
                                           (kt * 64 + c * 32 + g * 8) * 2);
        acc2[dn] = __builtin_amdgcn_mfma_f32_16x16x32_bf16(vf, pa, acc2[dn], 0, 0, 0);
      }
    }
  }

  if constexpr (!WRITE_P) {
    lsum += __shfl_xor(lsum, 16);
    lsum += __shfl_xor(lsum, 32);
    rinv = 1.0f / lsum;
#pragma unroll
    for (int dn = 0; dn < 2; ++dn)
#pragma unroll
      for (int i = 0; i < 4; ++i) acc2[dn][i] *= rinv;
  }

  float* Ct = (float*)myP;
#pragma unroll
  for (int dn = 0; dn < 2; ++dn)
#pragma unroll
    for (int i = 0; i < 4; ++i)
      Ct[r * 36 + dn * 16 + 4 * g + i] = acc2[dn][i];
  const int q2 = lane >> 2, pt = lane & 3;
  const f32x4 ca = *(const f32x4*)(myP + q2 * 144 + pt * 32);
  const f32x4 cb = *(const f32x4*)(myP + q2 * 144 + pt * 32 + 16);
  bf16x8 cv = {(bf16_t)ca[0], (bf16_t)ca[1], (bf16_t)ca[2], (bf16_t)ca[3],
               (bf16_t)cb[0], (bf16_t)cb[1], (bf16_t)cb[2], (bf16_t)cb[3]};
  *(bf16x8*)&ctx[((size_t)b * Ss + qrow0 + q2) * Ee + h * 32 + pt * 8] = cv;
}

// ================================================================ launcher
extern "C" void kernel_launch(void* const* d_in, const int* in_sizes, int n_in,
                              void* d_out, int out_size, void* d_ws, size_t ws_size,
                              hipStream_t stream) {
  const float* x     = (const float*)d_in[0];
  const float* q_w   = (const float*)d_in[1];
  const float* q_b   = (const float*)d_in[2];
  const float* k_w   = (const float*)d_in[3];
  const float* k_b   = (const float*)d_in[4];
  const float* v_w   = (const float*)d_in[5];
  const float* v_b   = (const float*)d_in[6];
  const float* ph_w1 = (const float*)d_in[7];
  const float* ph_b1 = (const float*)d_in[8];
  const float* ph_w2 = (const float*)d_in[9];
  const float* ph_b2 = (const float*)d_in[10];
  const float* in_w  = (const float*)d_in[11];
  const float* in_b  = (const float*)d_in[12];
  const float* out_w = (const float*)d_in[13];
  const float* out_b = (const float*)d_in[14];
  const float* fin_w = (const float*)d_in[15];
  const float* fin_b = (const float*)d_in[16];

  float* outp = (float*)d_out;
  float* attn_out = outp + (size_t)Ntok * Ee;

  char* ws = (char*)d_ws;
  size_t off = 0;
  auto alloc = [&](size_t bytes) -> void* {
    void* p = ws + off;
    off += (bytes + 255) & ~(size_t)255;
    return p;
  };
  bf16_t* x_bf  = (bf16_t*)alloc((size_t)Ntok * Ee * 2);
  bf16_t* wqkv  = (bf16_t*)alloc((size_t)E3 * Ee * 2);
  bf16_t* win   = (bf16_t*)alloc((size_t)E3 * Ee * 2);
  bf16_t* wout  = (bf16_t*)alloc((size_t)Ee * Ee * 2);
  bf16_t* wfin  = (bf16_t*)alloc((size_t)Ee * Ee * 2);
  bf16_t* woutT = (bf16_t*)alloc((size_t)Ee * Ee * 2);
  bf16_t* Wc    = (bf16_t*)alloc((size_t)Ee * Ee * 2);
  bf16_t* QKVb  = (bf16_t*)alloc((size_t)Ntok * E3 * 2);
  bf16_t* Vt    = (bf16_t*)alloc((size_t)Bb * Hh * Dd * Ss * 2);
  bf16_t* ctx   = (bf16_t*)alloc((size_t)Ntok * Ee * 2);
  bf16_t* qkv2  = (bf16_t*)alloc((size_t)Ntok * E3 * 2);
  bf16_t* v2t   = (bf16_t*)alloc((size_t)Bb * Hh * Dd * Ss * 2);
  bf16_t* ctx2  = (bf16_t*)alloc((size_t)Ntok * Ee * 2);
  float* part   = (float*)alloc((size_t)32 * 4 * 1024 * 4);
  float* xmean  = (float*)alloc(4096 * 4);
  float* hb     = (float*)alloc(4096 * 4);
  float* phase  = (float*)alloc(128 * 4);
  float* qkvb   = (float*)alloc(3072 * 4);
  float* bias_c = (float*)alloc(1024 * 4);

  hipFuncSetAttribute((const void*)attn_fused<1>,
                      hipFuncAttributeMaxDynamicSharedMemorySize, ATTN_LDS);
  hipFuncSetAttribute((const void*)attn_fused<0>,
                      hipFuncAttributeMaxDynamicSharedMemorySize, ATTN_LDS);

  // --- conversions + small prep
  conv_all<<<12288, 256, 0, stream>>>(x, q_w, k_w, v_w, in_w, out_w, fin_w,
                                      x_bf, wqkv, wqkv + (size_t)Ee * Ee,
                                      wqkv + (size_t)2 * Ee * Ee, win, wout, wfin);
  biasck<<<76, 256, 0, stream>>>(fin_w, out_b, fin_b, bias_c, q_b, k_b, v_b, qkvb);

  // --- phase chain (fp32)
  colmean_part<<<dim3(32, 4), 256, 0, stream>>>(x, part);
  colmean_fin<<<16, 256, 0, stream>>>(part, xmean);
  hgemm<<<64, 256, 0, stream>>>(xmean, ph_w1, ph_b1, hb);
  phasek<<<1, 128, 0, stream>>>(hb, ph_w2, ph_b2, phase);

  // --- Wc = fin_w @ out_w (128x64 tiles -> 128 blocks)
  transpose1024<<<dim3(16, 16), 256, 0, stream>>>(wout, woutT);
  gemm_n64<0><<<dim3(16, 8), 256, 0, stream>>>(wfin, nullptr, woutT, nullptr, nullptr,
                                               Wc, 1024, Ee, Ee, Ee);

  // --- fused QKV projection (phase applied to Q,K cols in epilogue)
  gemm_bt<4><<<dim3(24, 32), 256, 0, stream>>>(x_bf, wqkv, qkvb, QKVb, phase,
                                               1024, Ee, Ee, E3);
  transpose_v<<<dim3(8, 128), 256, 0, stream>>>(QKVb + 2048, E3, Vt);

  // --- attention 1 (P -> d_out + fused PV)
  attn_fused<1><<<dim3(8, 128), 512, ATTN_LDS, stream>>>(QKVb, QKVb + 1024, E3, Vt,
                                                         attn_out, ctx, SCALE2);

  // --- MHA on context
  gemm_bt<0><<<dim3(24, 32), 256, 0, stream>>>(ctx, win, in_b, qkv2, nullptr,
                                               1024, Ee, Ee, E3);
  transpose_v<<<dim3(8, 128), 256, 0, stream>>>(qkv2 + 2048, E3, v2t);
  attn_fused<0><<<dim3(8, 128), 512, ATTN_LDS, stream>>>(qkv2, qkv2 + 1024, E3, v2t,
                                                         nullptr, ctx2, SCALE2);

  // --- fused out_proj+residual+final (128x64 tiles -> 512 blocks):
  //     outp = ctx2@Wc^T + ctx@fin_w^T + bias_c
  gemm_n64<5><<<dim3(16, 32), 256, 0, stream>>>(ctx2, ctx, Wc, wfin, bias_c,
                                                outp, 2048, Ee, Ee, Ee);
}

// Round 10
// 458.629 us; speedup vs baseline: 1.1470x; 1.0867x over previous
//
#include <hip/hip_runtime.h>
#include <hip/hip_bf16.h>
#include <cstdint>
#include <cstddef>

typedef __bf16 bf16_t;
typedef __bf16 bf16x8 __attribute__((ext_vector_type(8)));
typedef __bf16 bf16x4 __attribute__((ext_vector_type(4)));
typedef float  f32x4  __attribute__((ext_vector_type(4)));

static constexpr int Bb = 4, Ss = 1024, Ee = 1024, Hh = 32, Dd = 32;
static constexpr int Ntok = Bb * Ss;   // 4096
static constexpr int E3   = 3 * Ee;    // 3072
static constexpr float SCALE2 = 0.25506060570135506f;   // (1/sqrt(32)) * log2(e)

__device__ __forceinline__ void gl_lds16(const void* g, void* l) {
  __builtin_amdgcn_global_load_lds(
      (const __attribute__((address_space(1))) void*)g,
      (__attribute__((address_space(3))) void*)l, 16, 0, 0);
}
__device__ __forceinline__ float fexp2(float x) { return __builtin_amdgcn_exp2f(x); }

// ---------------------------------------------------------------- mega-prep (narrow regions FIRST):
// [0,64) bias_c | [64,76) qkv bias concat | [76,204) colmean partials | [204,12492) f32->bf16
__global__ __launch_bounds__(256) void prep(const float* __restrict__ x,  const float* __restrict__ qw,
                                            const float* __restrict__ kw, const float* __restrict__ vw,
                                            const float* __restrict__ inw,const float* __restrict__ ow,
                                            const float* __restrict__ fw,
                                            const float* __restrict__ qb, const float* __restrict__ kb,
                                            const float* __restrict__ vb, const float* __restrict__ ob,
                                            const float* __restrict__ fb,
                                            bf16_t* __restrict__ xb, bf16_t* __restrict__ wqkv,
                                            bf16_t* __restrict__ winb, bf16_t* __restrict__ wob,
                                            bf16_t* __restrict__ wfb,
                                            float* __restrict__ qkvb, float* __restrict__ bias_c,
                                            float* __restrict__ part) {
  const int bx = blockIdx.x, t = threadIdx.x;
  if (bx < 64) {
    // bias_c[n] = fb[n] + sum_j fw[n][j]*ob[j]
    const int n = bx * 16 + (t >> 4), p = t & 15;
    const float* row = fw + (size_t)n * 1024 + p * 64;
    const float* obp = ob + p * 64;
    float s = 0.f;
    for (int j = 0; j < 64; ++j) s += row[j] * obp[j];
    s += __shfl_xor(s, 1);
    s += __shfl_xor(s, 2);
    s += __shfl_xor(s, 4);
    s += __shfl_xor(s, 8);
    if (p == 0) bias_c[n] = s + fb[n];
  } else if (bx < 76) {
    const int i = (bx - 64) * 256 + t;
    qkvb[i] = (i < 1024) ? qb[i] : (i < 2048) ? kb[i - 1024] : vb[i - 2048];
  } else if (bx < 204) {
    const int idx = bx - 76;                    // 128 blocks
    const int sc = idx & 31, b = idx >> 5;
    const float* base = x + ((size_t)b * Ss + sc * 32) * Ee;
    for (int k = 0; k < 4; ++k) {
      const int e = t + k * 256;
      float s = 0.f;
      for (int i = 0; i < 32; ++i) s += base[(size_t)i * Ee + e];
      part[((size_t)sc * 4 + b) * Ee + e] = s;
    }
  } else {
    const int i = (bx - 204) * 256 + t;
    const float* src; bf16_t* dst; int base;
    if      (i < 1048576) { src = x;   dst = xb;                      base = 0; }
    else if (i < 1310720) { src = qw;  dst = wqkv;                    base = 1048576; }
    else if (i < 1572864) { src = kw;  dst = wqkv + (size_t)Ee * Ee;  base = 1310720; }
    else if (i < 1835008) { src = vw;  dst = wqkv + (size_t)2*Ee*Ee;  base = 1572864; }
    else if (i < 2621440) { src = inw; dst = winb;                    base = 1835008; }
    else if (i < 2883584) { src = ow;  dst = wob;                     base = 2621440; }
    else                  { src = fw;  dst = wfb;                     base = 2883584; }
    const int j = i - base;
    const float4 v = *(const float4*)(src + (size_t)j * 4);
    bf16x4 o = {(bf16_t)v.x, (bf16_t)v.y, (bf16_t)v.z, (bf16_t)v.w};
    *(bf16x4*)(dst + (size_t)j * 4) = o;
  }
}

// ---------------------------------------------------------------- colmean finish
__global__ __launch_bounds__(256) void colmean_fin(const float* __restrict__ part,
                                                   float* __restrict__ xm) {
  const int idx = blockIdx.x * 256 + threadIdx.x;
  const int b = idx >> 10, e = idx & 1023;
  float s = 0.f;
  for (int sc = 0; sc < 32; ++sc) s += part[((size_t)sc * 4 + b) * Ee + e];
  xm[idx] = s * (1.0f / 1024.0f);
}

// ---------------------------------------------------------------- h = relu(xmean @ w1^T + b1), 64 blocks
__global__ __launch_bounds__(256) void hgemm(const float* __restrict__ xm,
                                             const float* __restrict__ w1,
                                             const float* __restrict__ b1,
                                             float* __restrict__ hout) {
  __shared__ float xl[4 * 1024];
  for (int i = threadIdx.x; i < 4096; i += 256) xl[i] = xm[i];
  __syncthreads();
  const int j = blockIdx.x * 16 + (threadIdx.x >> 4);
  const int p = threadIdx.x & 15;
  const float* wr = w1 + (size_t)j * Ee + p * 64;
  float a0 = 0.f, a1 = 0.f, a2 = 0.f, a3 = 0.f;
  const int e0 = p * 64;
#pragma unroll 8
  for (int e = 0; e < 64; ++e) {
    const float wv = wr[e];
    a0 += xl[e0 + e] * wv;
    a1 += xl[1024 + e0 + e] * wv;
    a2 += xl[2048 + e0 + e] * wv;
    a3 += xl[3072 + e0 + e] * wv;
  }
#pragma unroll
  for (int m = 1; m <= 8; m <<= 1) {
    a0 += __shfl_xor(a0, m);
    a1 += __shfl_xor(a1, m);
    a2 += __shfl_xor(a2, m);
    a3 += __shfl_xor(a3, m);
  }
  if (p == 0) {
    const float bb = b1[j];
    hout[j]        = fmaxf(a0 + bb, 0.f);
    hout[1024 + j] = fmaxf(a1 + bb, 0.f);
    hout[2048 + j] = fmaxf(a2 + bb, 0.f);
    hout[3072 + j] = fmaxf(a3 + bb, 0.f);
  }
}

// ---------------------------------------------------------------- phase = cos(h @ w2^T + b2), 128 blocks x 64
__global__ __launch_bounds__(64) void phasek(const float* __restrict__ hin,
                                             const float* __restrict__ w2,
                                             const float* __restrict__ b2,
                                             float* __restrict__ ph) {
  const int t = blockIdx.x;            // 0..127
  const int b = t >> 5, hh = t & 31;
  const int lane = threadIdx.x;
  const float* hr = hin + b * 1024;
  const float* wr = w2 + (size_t)hh * Ee;
  float s = 0.f;
  for (int j = lane; j < 1024; j += 64) s += hr[j] * wr[j];
#pragma unroll
  for (int m = 1; m < 64; m <<= 1) s += __shfl_xor(s, m);
  if (lane == 0) ph[t] = cosf(s + b2[hh]);
}

// ---------------------------------------------------------------- bf16 1024x1024 transpose
__global__ __launch_bounds__(256) void transpose1024(const bf16_t* __restrict__ in,
                                                     bf16_t* __restrict__ out) {
  __shared__ bf16_t t[64][72];
  const int jt = threadIdx.x >> 2, k16 = (threadIdx.x & 3) * 16;
  const int r0 = blockIdx.y * 64, c0 = blockIdx.x * 64;
  const bf16x8 a = *(const bf16x8*)(in + (size_t)(r0 + jt) * 1024 + c0 + k16);
  const bf16x8 b = *(const bf16x8*)(in + (size_t)(r0 + jt) * 1024 + c0 + k16 + 8);
  *(bf16x8*)&t[jt][k16] = a;
  *(bf16x8*)&t[jt][k16 + 8] = b;
  __syncthreads();
  bf16x8 v0, v1;
#pragma unroll
  for (int m = 0; m < 8; ++m) v0[m] = t[k16 + m][jt];
#pragma unroll
  for (int m = 0; m < 8; ++m) v1[m] = t[k16 + 8 + m][jt];
  *(bf16x8*)(out + (size_t)(c0 + jt) * 1024 + r0 + k16) = v0;
  *(bf16x8*)(out + (size_t)(c0 + jt) * 1024 + r0 + k16 + 8) = v1;
}

// ---------------------------------------------------------------- GEMM 128x128
// MODE 0: bf16 | 4: bf16 * phase (cols<2048). VT=1: cols>=2048 go TRANSPOSED to VtOut[bh][d][s].
template <int MODE, int VT>
__global__ __launch_bounds__(256) void gemm_bt(const bf16_t* __restrict__ A,
                                               const bf16_t* __restrict__ Bt,
                                               const float* __restrict__ bias,
                                               void* __restrict__ Cout,
                                               const float* __restrict__ phase,
                                               bf16_t* __restrict__ VtOut,
                                               int K, int lda, int ldb, int ldc) {
  __shared__ bf16_t As[128 * 32];
  __shared__ bf16_t Bs[128 * 32];
  const int tid = threadIdx.x;
  const int w = tid >> 6, lane = tid & 63;
  const int nwg = gridDim.x * gridDim.y;     // always % 8 == 0 here
  int flat = blockIdx.y * gridDim.x + blockIdx.x;
  flat = (flat & 7) * (nwg >> 3) + (flat >> 3);
  const int m0 = (flat / gridDim.x) * 128, n0 = (flat % gridDim.x) * 128;
  const int wr = (w >> 1) * 64, wc = (w & 1) * 64;
  const int r_ld = lane >> 2, c_ld = (lane & 3) * 8;
  const int rr = lane & 15, kk8 = (lane >> 4) * 8;
  f32x4 acc[4][4];
#pragma unroll
  for (int m = 0; m < 4; ++m)
#pragma unroll
    for (int n = 0; n < 4; ++n) acc[m][n] = f32x4{0.f, 0.f, 0.f, 0.f};

  for (int kt = 0; kt < K; kt += 32) {
#pragma unroll
    for (int j = 0; j < 2; ++j) {
      const int r0 = w * 16 + j * 64;
      gl_lds16(A + (size_t)(m0 + r0 + r_ld) * lda + kt + c_ld, &As[r0 * 32]);
      gl_lds16(Bt + (size_t)(n0 + r0 + r_ld) * ldb + kt + c_ld, &Bs[r0 * 32]);
    }
    __syncthreads();
    bf16x8 af[4], bfr[4];
#pragma unroll
    for (int m = 0; m < 4; ++m) af[m] = *(const bf16x8*)&As[(wr + m * 16 + rr) * 32 + kk8];
#pragma unroll
    for (int n = 0; n < 4; ++n) bfr[n] = *(const bf16x8*)&Bs[(wc + n * 16 + rr) * 32 + kk8];
#pragma unroll
    for (int m = 0; m < 4; ++m)
#pragma unroll
      for (int n = 0; n < 4; ++n)
        acc[m][n] = __builtin_amdgcn_mfma_f32_16x16x32_bf16(af[m], bfr[n], acc[m][n], 0, 0, 0);
    __syncthreads();
  }

  const int rr4 = (lane >> 4) * 4, cc = lane & 15;
#pragma unroll
  for (int m = 0; m < 4; ++m) {
#pragma unroll
    for (int n = 0; n < 4; ++n) {
      const int gr0 = m0 + wr + m * 16 + rr4;
      const int gc = n0 + wc + n * 16 + cc;
      const float bb = bias ? bias[gc] : 0.f;
      if (VT && gc >= 2048) {
        // transposed V write: Vt[bh][d][s], s = gr0&1023 (+i contiguous)
        bf16x4 pv;
#pragma unroll
        for (int i = 0; i < 4; ++i) pv[i] = (bf16_t)(acc[m][n][i] + bb);
        const int bh = ((gr0 >> 10) << 5) + ((gc - 2048) >> 5);
        *(bf16x4*)&VtOut[(size_t)bh * (Dd * Ss) + (size_t)(gc & 31) * Ss + (gr0 & 1023)] = pv;
      } else {
#pragma unroll
        for (int i = 0; i < 4; ++i) {
          const size_t idx = (size_t)(gr0 + i) * ldc + gc;
          float v = acc[m][n][i] + bb;
          if constexpr (MODE == 4) {
            if (gc < 2048) v *= phase[(((gr0 + i) >> 10) << 5) + ((gc >> 5) & 31)];
          }
          ((bf16_t*)Cout)[idx] = (bf16_t)v;
        }
      }
    }
  }
}

// ---------------------------------------------------------------- GEMM 128x64 (grid-starved shapes)
// MODE 0: bf16 | 5: fp32 nt, split-K at k=1024
template <int MODE>
__global__ __launch_bounds__(256) void gemm_n64(const bf16_t* __restrict__ A,
                                                const bf16_t* __restrict__ A2,
                                                const bf16_t* __restrict__ Bt,
                                                const bf16_t* __restrict__ Bt2,
                                                const float* __restrict__ bias,
                                                void* __restrict__ Cout,
                                                int K, int lda, int ldb, int ldc) {
  __shared__ bf16_t As[128 * 32];
  __shared__ bf16_t Bs[64 * 32];
  const int tid = threadIdx.x;
  const int w = tid >> 6, lane = tid & 63;
  const int nwg = gridDim.x * gridDim.y;   // % 8 == 0
  int flat = blockIdx.y * gridDim.x + blockIdx.x;
  flat = (flat & 7) * (nwg >> 3) + (flat >> 3);
  const int m0 = (flat / gridDim.x) * 128, n0 = (flat % gridDim.x) * 64;
  const int r_ld = lane >> 2, c_ld = (lane & 3) * 8;
  const int rr = lane & 15, kk8 = (lane >> 4) * 8;
  f32x4 acc[2][4];
#pragma unroll
  for (int m = 0; m < 2; ++m)
#pragma unroll
    for (int n = 0; n < 4; ++n) acc[m][n] = f32x4{0.f, 0.f, 0.f, 0.f};

  for (int kt = 0; kt < K; kt += 32) {
    const bf16_t* Ak = A;
    const bf16_t* Bk = Bt;
    int kk = kt;
    if constexpr (MODE == 5) {
      if (kt >= 1024) { Ak = A2; Bk = Bt2; kk = kt - 1024; }
    }
#pragma unroll
    for (int j = 0; j < 2; ++j) {
      const int r0 = w * 16 + j * 64;
      gl_lds16(Ak + (size_t)(m0 + r0 + r_ld) * lda + kk + c_ld, &As[r0 * 32]);
    }
    {
      const int r0 = w * 16;
      gl_lds16(Bk + (size_t)(n0 + r0 + r_ld) * ldb + kk + c_ld, &Bs[r0 * 32]);
    }
    __syncthreads();
    bf16x8 af[2], bfr[4];
#pragma unroll
    for (int m = 0; m < 2; ++m) af[m] = *(const bf16x8*)&As[(w * 32 + m * 16 + rr) * 32 + kk8];
#pragma unroll
    for (int n = 0; n < 4; ++n) bfr[n] = *(const bf16x8*)&Bs[(n * 16 + rr) * 32 + kk8];
#pragma unroll
    for (int m = 0; m < 2; ++m)
#pragma unroll
      for (int n = 0; n < 4; ++n)
        acc[m][n] = __builtin_amdgcn_mfma_f32_16x16x32_bf16(af[m], bfr[n], acc[m][n], 0, 0, 0);
    __syncthreads();
  }

  const int rr4 = (lane >> 4) * 4, cc = lane & 15;
#pragma unroll
  for (int m = 0; m < 2; ++m) {
#pragma unroll
    for (int n = 0; n < 4; ++n) {
      const int gr0 = m0 + w * 32 + m * 16 + rr4;
      const int gc = n0 + n * 16 + cc;
      const float bb = bias ? bias[gc] : 0.f;
#pragma unroll
      for (int i = 0; i < 4; ++i) {
        const size_t idx = (size_t)(gr0 + i) * ldc + gc;
        float v = acc[m][n][i] + bb;
        if constexpr (MODE == 5) __builtin_nontemporal_store(v, (float*)Cout + idx);
        else ((bf16_t*)Cout)[idx] = (bf16_t)v;
      }
    }
  }
}

// ---------------------------------------------------------------- fused attention (R6 structure, nt P store)
static constexpr int K_PLANE_B = 16400;           // 1025*16 B per k-plane
static constexpr int V_OFF_B   = 4 * K_PLANE_B;   // 65600
static constexpr int V_ROW_B   = 2064;            // 1032 bf16
static constexpr int P_OFF_B   = V_OFF_B + 32 * V_ROW_B;  // 131648
static constexpr int P_WAVE_B  = 2304;            // 16 rows * 144 B
static constexpr int ATTN_LDS  = P_OFF_B + 8 * P_WAVE_B;  // 150080

template <int WRITE_P>
__global__ __launch_bounds__(512) void attn_fused(const bf16_t* __restrict__ Qm,
                                                  const bf16_t* __restrict__ Km, int rs,
                                                  const bf16_t* __restrict__ Vt,
                                                  float* __restrict__ Pout,
                                                  bf16_t* __restrict__ ctx, float scale2) {
  extern __shared__ char smem[];
  char* Kl = smem;
  char* Vl = smem + V_OFF_B;
  const int tid = threadIdx.x, lane = tid & 63, w = tid >> 6;
  const int g = lane >> 4, r = lane & 15;
  int flat = blockIdx.y * 8 + blockIdx.x;
  flat = (flat & 7) * 128 + (flat >> 3);             // XCD: blocks of one bh co-XCD
  const int bh = flat >> 3, xb = flat & 7;
  const int b = bh >> 5, h = bh & 31;
  char* myP = smem + P_OFF_B + w * P_WAVE_B;

  {
    const bf16_t* Kbase = Km + (size_t)b * Ss * rs + h * 32;
    const int pg = w >> 1, hh = w & 1;
#pragma unroll
    for (int c = 0; c < 8; ++c) {
      const int row0 = hh * 512 + c * 64;
      gl_lds16(Kbase + (size_t)(row0 + lane) * rs + pg * 8, Kl + pg * K_PLANE_B + row0 * 16);
    }
  }
  {
    const bf16_t* vsrc = Vt + (size_t)bh * (Dd * Ss);
#pragma unroll
    for (int rr2 = 0; rr2 < 4; ++rr2) {
      const int row = w * 4 + rr2;
#pragma unroll
      for (int c = 0; c < 2; ++c)
        gl_lds16(vsrc + (size_t)row * Ss + c * 512 + lane * 8, Vl + row * V_ROW_B + c * 1024);
    }
  }
  const int qrow0 = xb * 128 + w * 16;
  const bf16x8 qraw = *(const bf16x8*)(Qm + ((size_t)b * Ss + qrow0 + r) * rs + h * 32 + g * 8);
  bf16x8 qf;
#pragma unroll
  for (int i = 0; i < 8; ++i) qf[i] = (bf16_t)((float)qraw[i] * scale2);
  __syncthreads();

  const f32x4 zero = {0.f, 0.f, 0.f, 0.f};
  float lsum = 0.f, rinv = 1.f;

  if constexpr (WRITE_P) {
    for (int kt = 0; kt < 16; ++kt) {
#pragma unroll
      for (int n = 0; n < 4; ++n) {
        const int key = kt * 64 + n * 16 + r;
        const bf16x8 kf = *(const bf16x8*)(Kl + g * K_PLANE_B + key * 16);
        const f32x4 s = __builtin_amdgcn_mfma_f32_16x16x32_bf16(kf, qf, zero, 0, 0, 0);
#pragma unroll
        for (int i = 0; i < 4; ++i) lsum += fexp2(s[i]);
      }
    }
    lsum += __shfl_xor(lsum, 16);
    lsum += __shfl_xor(lsum, 32);
    rinv = 1.0f / lsum;
  }

  f32x4 acc2[2] = {zero, zero};
  const size_t pbase = (size_t)bh * Ss * Ss;

  for (int kt = 0; kt < 16; ++kt) {
    float p[4][4];
#pragma unroll
    for (int n = 0; n < 4; ++n) {
      const int key = kt * 64 + n * 16 + r;
      const bf16x8 kf = *(const bf16x8*)(Kl + g * K_PLANE_B + key * 16);
      const f32x4 s = __builtin_amdgcn_mfma_f32_16x16x32_bf16(kf, qf, zero, 0, 0, 0);
#pragma unroll
      for (int i = 0; i < 4; ++i) {
        float e = fexp2(s[i]);
        if constexpr (WRITE_P) e *= rinv;
        else lsum += e;
        p[n][i] = e;
      }
      bf16x4 pw = {(bf16_t)p[n][0], (bf16_t)p[n][1], (bf16_t)p[n][2], (bf16_t)p[n][3]};
      *(bf16x4*)(myP + r * 144 + (n * 16 + g * 4) * 2) = pw;
      if constexpr (WRITE_P) {
        f32x4 w4 = {p[n][0], p[n][1], p[n][2], p[n][3]};
        __builtin_nontemporal_store(
            w4, (f32x4*)&Pout[pbase + (size_t)(qrow0 + r) * Ss + kt * 64 + n * 16 + 4 * g]);
      }
    }
#pragma unroll
    for (int c = 0; c < 2; ++c) {
      const bf16x8 pa = *(const bf16x8*)(myP + r * 144 + (c * 32 + 8 * g) * 2);
#pragma unroll
      for (int dn = 0; dn < 2; ++dn) {
        const bf16x8 vf = *(const bf16x8*)(Vl + (dn * 16 + r) * V_ROW_B +
                                           (kt * 64 + c * 32 + g * 8) * 2);
        acc2[dn] = __builtin_amdgcn_mfma_f32_16x16x32_bf16(vf, pa, acc2[dn], 0, 0, 0);
      }
    }
  }

  if constexpr (!WRITE_P) {
    lsum += __shfl_xor(lsum, 16);
    lsum += __shfl_xor(lsum, 32);
    rinv = 1.0f / lsum;
#pragma unroll
    for (int dn = 0; dn < 2; ++dn)
#pragma unroll
      for (int i = 0; i < 4; ++i) acc2[dn][i] *= rinv;
  }

  float* Ct = (float*)myP;
#pragma unroll
  for (int dn = 0; dn < 2; ++dn)
#pragma unroll
    for (int i = 0; i < 4; ++i)
      Ct[r * 36 + dn * 16 + 4 * g + i] = acc2[dn][i];
  const int q2 = lane >> 2, pt = lane & 3;
  const f32x4 ca = *(const f32x4*)(myP + q2 * 144 + pt * 32);
  const f32x4 cb = *(const f32x4*)(myP + q2 * 144 + pt * 32 + 16);
  bf16x8 cv = {(bf16_t)ca[0], (bf16_t)ca[1], (bf16_t)ca[2], (bf16_t)ca[3],
               (bf16_t)cb[0], (bf16_t)cb[1], (bf16_t)cb[2], (bf16_t)cb[3]};
  *(bf16x8*)&ctx[((size_t)b * Ss + qrow0 + q2) * Ee + h * 32 + pt * 8] = cv;
}

// ================================================================ launcher
extern "C" void kernel_launch(void* const* d_in, const int* in_sizes, int n_in,
                              void* d_out, int out_size, void* d_ws, size_t ws_size,
                              hipStream_t stream) {
  const float* x     = (const float*)d_in[0];
  const float* q_w   = (const float*)d_in[1];
  const float* q_b   = (const float*)d_in[2];
  const float* k_w   = (const float*)d_in[3];
  const float* k_b   = (const float*)d_in[4];
  const float* v_w   = (const float*)d_in[5];
  const float* v_b   = (const float*)d_in[6];
  const float* ph_w1 = (const float*)d_in[7];
  const float* ph_b1 = (const float*)d_in[8];
  const float* ph_w2 = (const float*)d_in[9];
  const float* ph_b2 = (const float*)d_in[10];
  const float* in_w  = (const float*)d_in[11];
  const float* in_b  = (const float*)d_in[12];
  const float* out_w = (const float*)d_in[13];
  const float* out_b = (const float*)d_in[14];
  const float* fin_w = (const float*)d_in[15];
  const float* fin_b = (const float*)d_in[16];

  float* outp = (float*)d_out;
  float* attn_out = outp + (size_t)Ntok * Ee;

  char* ws = (char*)d_ws;
  size_t off = 0;
  auto alloc = [&](size_t bytes) -> void* {
    void* p = ws + off;
    off += (bytes + 255) & ~(size_t)255;
    return p;
  };
  bf16_t* x_bf  = (bf16_t*)alloc((size_t)Ntok * Ee * 2);
  bf16_t* wqkv  = (bf16_t*)alloc((size_t)E3 * Ee * 2);
  bf16_t* win   = (bf16_t*)alloc((size_t)E3 * Ee * 2);
  bf16_t* wout  = (bf16_t*)alloc((size_t)Ee * Ee * 2);
  bf16_t* wfin  = (bf16_t*)alloc((size_t)Ee * Ee * 2);
  bf16_t* woutT = (bf16_t*)alloc((size_t)Ee * Ee * 2);
  bf16_t* Wc    = (bf16_t*)alloc((size_t)Ee * Ee * 2);
  bf16_t* QKVb  = (bf16_t*)alloc((size_t)Ntok * E3 * 2);
  bf16_t* Vt    = (bf16_t*)alloc((size_t)Bb * Hh * Dd * Ss * 2);
  bf16_t* ctx   = (bf16_t*)alloc((size_t)Ntok * Ee * 2);
  bf16_t* qkv2  = (bf16_t*)alloc((size_t)Ntok * E3 * 2);
  bf16_t* v2t   = (bf16_t*)alloc((size_t)Bb * Hh * Dd * Ss * 2);
  bf16_t* ctx2  = (bf16_t*)alloc((size_t)Ntok * Ee * 2);
  float* part   = (float*)alloc((size_t)32 * 4 * 1024 * 4);
  float* xmean  = (float*)alloc(4096 * 4);
  float* hb     = (float*)alloc(4096 * 4);
  float* phase  = (float*)alloc(128 * 4);
  float* qkvb   = (float*)alloc(3072 * 4);
  float* bias_c = (float*)alloc(1024 * 4);

  hipFuncSetAttribute((const void*)attn_fused<1>,
                      hipFuncAttributeMaxDynamicSharedMemorySize, ATTN_LDS);
  hipFuncSetAttribute((const void*)attn_fused<0>,
                      hipFuncAttributeMaxDynamicSharedMemorySize, ATTN_LDS);

  // 1. mega-prep (narrow regions first; conversions wide)
  prep<<<12492, 256, 0, stream>>>(x, q_w, k_w, v_w, in_w, out_w, fin_w,
                                  q_b, k_b, v_b, out_b, fin_b,
                                  x_bf, wqkv, win, wout, wfin, qkvb, bias_c, part);
  // 2-4. phase chain (all wide enough)
  colmean_fin<<<16, 256, 0, stream>>>(part, xmean);
  hgemm<<<64, 256, 0, stream>>>(xmean, ph_w1, ph_b1, hb);
  phasek<<<128, 64, 0, stream>>>(hb, ph_w2, ph_b2, phase);

  // 5-6. Wc = fin_w @ out_w (128x64 tiles)
  transpose1024<<<dim3(16, 16), 256, 0, stream>>>(wout, woutT);
  gemm_n64<0><<<dim3(16, 8), 256, 0, stream>>>(wfin, nullptr, woutT, nullptr, nullptr,
                                               Wc, 1024, Ee, Ee, Ee);

  // 7. fused QKV projection; V written transposed straight to Vt
  gemm_bt<4, 1><<<dim3(24, 32), 256, 0, stream>>>(x_bf, wqkv, qkvb, QKVb, phase, Vt,
                                                  1024, Ee, Ee, E3);
  // 8. attention 1 (P -> d_out + fused PV)
  attn_fused<1><<<dim3(8, 128), 512, ATTN_LDS, stream>>>(QKVb, QKVb + 1024, E3, Vt,
                                                         attn_out, ctx, SCALE2);
  // 9. in_proj; V2 written transposed straight to v2t
  gemm_bt<0, 1><<<dim3(24, 32), 256, 0, stream>>>(ctx, win, in_b, qkv2, nullptr, v2t,
                                                  1024, Ee, Ee, E3);
  // 10. attention 2 (flash)
  attn_fused<0><<<dim3(8, 128), 512, ATTN_LDS, stream>>>(qkv2, qkv2 + 1024, E3, v2t,
                                                         nullptr, ctx2, SCALE2);
  // 11. fused out_proj+residual+final (128x64 tiles):
  //     outp = ctx2@Wc^T + ctx@fin_w^T + bias_c
  gemm_n64<5><<<dim3(16, 32), 256, 0, stream>>>(ctx2, ctx, Wc, wfin, bias_c,
                                                outp, 2048, Ee, Ee, Ee);
}

// Round 11
// 447.136 us; speedup vs baseline: 1.1765x; 1.0257x over previous
//
#include <hip/hip_runtime.h>
#include <hip/hip_bf16.h>
#include <cstdint>
#include <cstddef>

typedef __bf16 bf16_t;
typedef __bf16 bf16x8 __attribute__((ext_vector_type(8)));
typedef __bf16 bf16x4 __attribute__((ext_vector_type(4)));
typedef float  f32x4  __attribute__((ext_vector_type(4)));

static constexpr int Bb = 4, Ss = 1024, Ee = 1024, Hh = 32, Dd = 32;
static constexpr int Ntok = Bb * Ss;   // 4096
static constexpr int E3   = 3 * Ee;    // 3072
static constexpr float SCALE2 = 0.25506060570135506f;   // (1/sqrt(32)) * log2(e)

__device__ __forceinline__ void gl_lds16(const void* g, void* l) {
  __builtin_amdgcn_global_load_lds(
      (const __attribute__((address_space(1))) void*)g,
      (__attribute__((address_space(3))) void*)l, 16, 0, 0);
}
__device__ __forceinline__ float fexp2(float x) { return __builtin_amdgcn_exp2f(x); }

// ---------------------------------------------------------------- mega-prep (narrow regions FIRST):
// [0,64) bias_c | [64,76) qkv bias concat | [76,204) colmean partials | [204,12492) f32->bf16
__global__ __launch_bounds__(256) void prep(const float* __restrict__ x,  const float* __restrict__ qw,
                                            const float* __restrict__ kw, const float* __restrict__ vw,
                                            const float* __restrict__ inw,const float* __restrict__ ow,
                                            const float* __restrict__ fw,
                                            const float* __restrict__ qb, const float* __restrict__ kb,
                                            const float* __restrict__ vb, const float* __restrict__ ob,
                                            const float* __restrict__ fb,
                                            bf16_t* __restrict__ xb, bf16_t* __restrict__ wqkv,
                                            bf16_t* __restrict__ winb, bf16_t* __restrict__ wob,
                                            bf16_t* __restrict__ wfb,
                                            float* __restrict__ qkvb, float* __restrict__ bias_c,
                                            float* __restrict__ part) {
  const int bx = blockIdx.x, t = threadIdx.x;
  if (bx < 64) {
    const int n = bx * 16 + (t >> 4), p = t & 15;
    const float* row = fw + (size_t)n * 1024 + p * 64;
    const float* obp = ob + p * 64;
    float s = 0.f;
    for (int j = 0; j < 64; ++j) s += row[j] * obp[j];
    s += __shfl_xor(s, 1);
    s += __shfl_xor(s, 2);
    s += __shfl_xor(s, 4);
    s += __shfl_xor(s, 8);
    if (p == 0) bias_c[n] = s + fb[n];
  } else if (bx < 76) {
    const int i = (bx - 64) * 256 + t;
    qkvb[i] = (i < 1024) ? qb[i] : (i < 2048) ? kb[i - 1024] : vb[i - 2048];
  } else if (bx < 204) {
    const int idx = bx - 76;
    const int sc = idx & 31, b = idx >> 5;
    const float* base = x + ((size_t)b * Ss + sc * 32) * Ee;
    for (int k = 0; k < 4; ++k) {
      const int e = t + k * 256;
      float s = 0.f;
      for (int i = 0; i < 32; ++i) s += base[(size_t)i * Ee + e];
      part[((size_t)sc * 4 + b) * Ee + e] = s;
    }
  } else {
    const int i = (bx - 204) * 256 + t;
    const float* src; bf16_t* dst; int base;
    if      (i < 1048576) { src = x;   dst = xb;                      base = 0; }
    else if (i < 1310720) { src = qw;  dst = wqkv;                    base = 1048576; }
    else if (i < 1572864) { src = kw;  dst = wqkv + (size_t)Ee * Ee;  base = 1310720; }
    else if (i < 1835008) { src = vw;  dst = wqkv + (size_t)2*Ee*Ee;  base = 1572864; }
    else if (i < 2621440) { src = inw; dst = winb;                    base = 1835008; }
    else if (i < 2883584) { src = ow;  dst = wob;                     base = 2621440; }
    else                  { src = fw;  dst = wfb;                     base = 2883584; }
    const int j = i - base;
    const float4 v = *(const float4*)(src + (size_t)j * 4);
    bf16x4 o = {(bf16_t)v.x, (bf16_t)v.y, (bf16_t)v.z, (bf16_t)v.w};
    *(bf16x4*)(dst + (size_t)j * 4) = o;
  }
}

// ---------------------------------------------------------------- colmean finish [0,16) + wout transpose [16,272)
__global__ __launch_bounds__(256) void fin_t1024(const float* __restrict__ part,
                                                 float* __restrict__ xm,
                                                 const bf16_t* __restrict__ win,
                                                 bf16_t* __restrict__ wout) {
  if (blockIdx.x < 16) {
    const int idx = blockIdx.x * 256 + threadIdx.x;
    const int b = idx >> 10, e = idx & 1023;
    float s = 0.f;
    for (int sc = 0; sc < 32; ++sc) s += part[((size_t)sc * 4 + b) * Ee + e];
    xm[idx] = s * (1.0f / 1024.0f);
    return;
  }
  __shared__ bf16_t tl[64][72];
  const int i = blockIdx.x - 16;                 // 0..255 -> (bxx, by)
  const int c0 = (i & 15) * 64, r0 = (i >> 4) * 64;
  const int jt = threadIdx.x >> 2, k16 = (threadIdx.x & 3) * 16;
  const bf16x8 a = *(const bf16x8*)(win + (size_t)(r0 + jt) * 1024 + c0 + k16);
  const bf16x8 b = *(const bf16x8*)(win + (size_t)(r0 + jt) * 1024 + c0 + k16 + 8);
  *(bf16x8*)&tl[jt][k16] = a;
  *(bf16x8*)&tl[jt][k16 + 8] = b;
  __syncthreads();
  bf16x8 v0, v1;
#pragma unroll
  for (int m = 0; m < 8; ++m) v0[m] = tl[k16 + m][jt];
#pragma unroll
  for (int m = 0; m < 8; ++m) v1[m] = tl[k16 + 8 + m][jt];
  *(bf16x8*)(wout + (size_t)(c0 + jt) * 1024 + r0 + k16) = v0;
  *(bf16x8*)(wout + (size_t)(c0 + jt) * 1024 + r0 + k16 + 8) = v1;
}

// ---------------------------------------------------------------- h = relu(xmean @ w1^T + b1), 64 blocks
__global__ __launch_bounds__(256) void hgemm(const float* __restrict__ xm,
                                             const float* __restrict__ w1,
                                             const float* __restrict__ b1,
                                             float* __restrict__ hout) {
  __shared__ float xl[4 * 1024];
  for (int i = threadIdx.x; i < 4096; i += 256) xl[i] = xm[i];
  __syncthreads();
  const int j = blockIdx.x * 16 + (threadIdx.x >> 4);
  const int p = threadIdx.x & 15;
  const float* wr = w1 + (size_t)j * Ee + p * 64;
  float a0 = 0.f, a1 = 0.f, a2 = 0.f, a3 = 0.f;
  const int e0 = p * 64;
#pragma unroll 8
  for (int e = 0; e < 64; ++e) {
    const float wv = wr[e];
    a0 += xl[e0 + e] * wv;
    a1 += xl[1024 + e0 + e] * wv;
    a2 += xl[2048 + e0 + e] * wv;
    a3 += xl[3072 + e0 + e] * wv;
  }
#pragma unroll
  for (int m = 1; m <= 8; m <<= 1) {
    a0 += __shfl_xor(a0, m);
    a1 += __shfl_xor(a1, m);
    a2 += __shfl_xor(a2, m);
    a3 += __shfl_xor(a3, m);
  }
  if (p == 0) {
    const float bb = b1[j];
    hout[j]        = fmaxf(a0 + bb, 0.f);
    hout[1024 + j] = fmaxf(a1 + bb, 0.f);
    hout[2048 + j] = fmaxf(a2 + bb, 0.f);
    hout[3072 + j] = fmaxf(a3 + bb, 0.f);
  }
}

// ---------------------------------------------------------------- phase = cos(h @ w2^T + b2), 128 blocks x 64
__global__ __launch_bounds__(64) void phasek(const float* __restrict__ hin,
                                             const float* __restrict__ w2,
                                             const float* __restrict__ b2,
                                             float* __restrict__ ph) {
  const int t = blockIdx.x;
  const int b = t >> 5, hh = t & 31;
  const int lane = threadIdx.x;
  const float* hr = hin + b * 1024;
  const float* wr = w2 + (size_t)hh * Ee;
  float s = 0.f;
  for (int j = lane; j < 1024; j += 64) s += hr[j] * wr[j];
#pragma unroll
  for (int m = 1; m < 64; m <<= 1) s += __shfl_xor(s, m);
  if (lane == 0) ph[t] = cosf(s + b2[hh]);
}

// ---------------------------------------------------------------- merged QKV (768 blocks) + Wc (128 blocks)
// QKV: C[4096][3072] = x_bf @ wqkv^T + qkvb; V cols (>=2048) written transposed to Vt.
// Wc:  Wc[1024][1024] = wfin @ woutT^T (128x64 tiles).
__global__ __launch_bounds__(256) void qkv_wc(const bf16_t* __restrict__ A,
                                              const bf16_t* __restrict__ Bt,
                                              const float* __restrict__ bias,
                                              bf16_t* __restrict__ Cout,
                                              bf16_t* __restrict__ VtOut,
                                              const bf16_t* __restrict__ Aw,
                                              const bf16_t* __restrict__ Btw,
                                              bf16_t* __restrict__ WcOut) {
  const int tid = threadIdx.x;
  const int w = tid >> 6, lane = tid & 63;
  const int r_ld = lane >> 2, c_ld = (lane & 3) * 8;
  const int rr = lane & 15, kk8 = (lane >> 4) * 8;

  if (blockIdx.x < 768) {
    __shared__ bf16_t As[128 * 32];
    __shared__ bf16_t Bs[128 * 32];
    int flat = blockIdx.x;
    flat = (flat & 7) * 96 + (flat >> 3);          // XCD swizzle, nwg=768
    const int m0 = (flat / 24) * 128, n0 = (flat % 24) * 128;
    const int wr = (w >> 1) * 64, wc = (w & 1) * 64;
    f32x4 acc[4][4];
#pragma unroll
    for (int m = 0; m < 4; ++m)
#pragma unroll
      for (int n = 0; n < 4; ++n) acc[m][n] = f32x4{0.f, 0.f, 0.f, 0.f};
    for (int kt = 0; kt < 1024; kt += 32) {
#pragma unroll
      for (int j = 0; j < 2; ++j) {
        const int r0 = w * 16 + j * 64;
        gl_lds16(A + (size_t)(m0 + r0 + r_ld) * Ee + kt + c_ld, &As[r0 * 32]);
        gl_lds16(Bt + (size_t)(n0 + r0 + r_ld) * Ee + kt + c_ld, &Bs[r0 * 32]);
      }
      __syncthreads();
      bf16x8 af[4], bfr[4];
#pragma unroll
      for (int m = 0; m < 4; ++m) af[m] = *(const bf16x8*)&As[(wr + m * 16 + rr) * 32 + kk8];
#pragma unroll
      for (int n = 0; n < 4; ++n) bfr[n] = *(const bf16x8*)&Bs[(wc + n * 16 + rr) * 32 + kk8];
#pragma unroll
      for (int m = 0; m < 4; ++m)
#pragma unroll
        for (int n = 0; n < 4; ++n)
          acc[m][n] = __builtin_amdgcn_mfma_f32_16x16x32_bf16(af[m], bfr[n], acc[m][n], 0, 0, 0);
      __syncthreads();
    }
    const int rr4 = (lane >> 4) * 4, cc = lane & 15;
#pragma unroll
    for (int m = 0; m < 4; ++m) {
#pragma unroll
      for (int n = 0; n < 4; ++n) {
        const int gr0 = m0 + wr + m * 16 + rr4;
        const int gc = n0 + wc + n * 16 + cc;
        const float bb = bias[gc];
        if (gc >= 2048) {
          bf16x4 pv;
#pragma unroll
          for (int i = 0; i < 4; ++i) pv[i] = (bf16_t)(acc[m][n][i] + bb);
          const int bh = ((gr0 >> 10) << 5) + ((gc - 2048) >> 5);
          *(bf16x4*)&VtOut[(size_t)bh * (Dd * Ss) + (size_t)(gc & 31) * Ss + (gr0 & 1023)] = pv;
        } else {
#pragma unroll
          for (int i = 0; i < 4; ++i)
            Cout[(size_t)(gr0 + i) * E3 + gc] = (bf16_t)(acc[m][n][i] + bb);
        }
      }
    }
  } else {
    __shared__ bf16_t As[128 * 32];
    __shared__ bf16_t Bs[64 * 32];
    int flat = blockIdx.x - 768;                   // 0..127
    flat = (flat & 7) * 16 + (flat >> 3);          // XCD swizzle, nwg=128
    const int m0 = (flat / 16) * 128, n0 = (flat % 16) * 64;
    f32x4 acc[2][4];
#pragma unroll
    for (int m = 0; m < 2; ++m)
#pragma unroll
      for (int n = 0; n < 4; ++n) acc[m][n] = f32x4{0.f, 0.f, 0.f, 0.f};
    for (int kt = 0; kt < 1024; kt += 32) {
#pragma unroll
      for (int j = 0; j < 2; ++j) {
        const int r0 = w * 16 + j * 64;
        gl_lds16(Aw + (size_t)(m0 + r0 + r_ld) * Ee + kt + c_ld, &As[r0 * 32]);
      }
      {
        const int r0 = w * 16;
        gl_lds16(Btw + (size_t)(n0 + r0 + r_ld) * Ee + kt + c_ld, &Bs[r0 * 32]);
      }
      __syncthreads();
      bf16x8 af[2], bfr[4];
#pragma unroll
      for (int m = 0; m < 2; ++m) af[m] = *(const bf16x8*)&As[(w * 32 + m * 16 + rr) * 32 + kk8];
#pragma unroll
      for (int n = 0; n < 4; ++n) bfr[n] = *(const bf16x8*)&Bs[(n * 16 + rr) * 32 + kk8];
#pragma unroll
      for (int m = 0; m < 2; ++m)
#pragma unroll
        for (int n = 0; n < 4; ++n)
          acc[m][n] = __builtin_amdgcn_mfma_f32_16x16x32_bf16(af[m], bfr[n], acc[m][n], 0, 0, 0);
      __syncthreads();
    }
    const int rr4 = (lane >> 4) * 4, cc = lane & 15;
#pragma unroll
    for (int m = 0; m < 2; ++m)
#pragma unroll
      for (int n = 0; n < 4; ++n) {
        const int gr0 = m0 + w * 32 + m * 16 + rr4;
        const int gc = n0 + n * 16 + cc;
#pragma unroll
        for (int i = 0; i < 4; ++i)
          WcOut[(size_t)(gr0 + i) * Ee + gc] = (bf16_t)acc[m][n][i];
      }
  }
}

// ---------------------------------------------------------------- GEMM 128x128, bf16; cols>=2048 transposed to VtOut
__global__ __launch_bounds__(256) void gemm_bt(const bf16_t* __restrict__ A,
                                               const bf16_t* __restrict__ Bt,
                                               const float* __restrict__ bias,
                                               bf16_t* __restrict__ Cout,
                                               bf16_t* __restrict__ VtOut,
                                               int K, int lda, int ldb, int ldc) {
  __shared__ bf16_t As[128 * 32];
  __shared__ bf16_t Bs[128 * 32];
  const int tid = threadIdx.x;
  const int w = tid >> 6, lane = tid & 63;
  const int nwg = gridDim.x * gridDim.y;
  int flat = blockIdx.y * gridDim.x + blockIdx.x;
  flat = (flat & 7) * (nwg >> 3) + (flat >> 3);
  const int m0 = (flat / gridDim.x) * 128, n0 = (flat % gridDim.x) * 128;
  const int wr = (w >> 1) * 64, wc = (w & 1) * 64;
  const int r_ld = lane >> 2, c_ld = (lane & 3) * 8;
  const int rr = lane & 15, kk8 = (lane >> 4) * 8;
  f32x4 acc[4][4];
#pragma unroll
  for (int m = 0; m < 4; ++m)
#pragma unroll
    for (int n = 0; n < 4; ++n) acc[m][n] = f32x4{0.f, 0.f, 0.f, 0.f};

  for (int kt = 0; kt < K; kt += 32) {
#pragma unroll
    for (int j = 0; j < 2; ++j) {
      const int r0 = w * 16 + j * 64;
      gl_lds16(A + (size_t)(m0 + r0 + r_ld) * lda + kt + c_ld, &As[r0 * 32]);
      gl_lds16(Bt + (size_t)(n0 + r0 + r_ld) * ldb + kt + c_ld, &Bs[r0 * 32]);
    }
    __syncthreads();
    bf16x8 af[4], bfr[4];
#pragma unroll
    for (int m = 0; m < 4; ++m) af[m] = *(const bf16x8*)&As[(wr + m * 16 + rr) * 32 + kk8];
#pragma unroll
    for (int n = 0; n < 4; ++n) bfr[n] = *(const bf16x8*)&Bs[(wc + n * 16 + rr) * 32 + kk8];
#pragma unroll
    for (int m = 0; m < 4; ++m)
#pragma unroll
      for (int n = 0; n < 4; ++n)
        acc[m][n] = __builtin_amdgcn_mfma_f32_16x16x32_bf16(af[m], bfr[n], acc[m][n], 0, 0, 0);
    __syncthreads();
  }

  const int rr4 = (lane >> 4) * 4, cc = lane & 15;
#pragma unroll
  for (int m = 0; m < 4; ++m) {
#pragma unroll
    for (int n = 0; n < 4; ++n) {
      const int gr0 = m0 + wr + m * 16 + rr4;
      const int gc = n0 + wc + n * 16 + cc;
      const float bb = bias ? bias[gc] : 0.f;
      if (gc >= 2048) {
        bf16x4 pv;
#pragma unroll
        for (int i = 0; i < 4; ++i) pv[i] = (bf16_t)(acc[m][n][i] + bb);
        const int bh = ((gr0 >> 10) << 5) + ((gc - 2048) >> 5);
        *(bf16x4*)&VtOut[(size_t)bh * (Dd * Ss) + (size_t)(gc & 31) * Ss + (gr0 & 1023)] = pv;
      } else {
#pragma unroll
        for (int i = 0; i < 4; ++i)
          Cout[(size_t)(gr0 + i) * ldc + gc] = (bf16_t)(acc[m][n][i] + bb);
      }
    }
  }
}

// ---------------------------------------------------------------- GEMM 128x64, fp32 nt out, split-K at k=1024
__global__ __launch_bounds__(256) void gemm_fin(const bf16_t* __restrict__ A,
                                                const bf16_t* __restrict__ A2,
                                                const bf16_t* __restrict__ Bt,
                                                const bf16_t* __restrict__ Bt2,
                                                const float* __restrict__ bias,
                                                float* __restrict__ Cout,
                                                int K, int lda, int ldb, int ldc) {
  __shared__ bf16_t As[128 * 32];
  __shared__ bf16_t Bs[64 * 32];
  const int tid = threadIdx.x;
  const int w = tid >> 6, lane = tid & 63;
  const int nwg = gridDim.x * gridDim.y;
  int flat = blockIdx.y * gridDim.x + blockIdx.x;
  flat = (flat & 7) * (nwg >> 3) + (flat >> 3);
  const int m0 = (flat / gridDim.x) * 128, n0 = (flat % gridDim.x) * 64;
  const int r_ld = lane >> 2, c_ld = (lane & 3) * 8;
  const int rr = lane & 15, kk8 = (lane >> 4) * 8;
  f32x4 acc[2][4];
#pragma unroll
  for (int m = 0; m < 2; ++m)
#pragma unroll
    for (int n = 0; n < 4; ++n) acc[m][n] = f32x4{0.f, 0.f, 0.f, 0.f};

  for (int kt = 0; kt < K; kt += 32) {
    const bf16_t* Ak = A;
    const bf16_t* Bk = Bt;
    int kk = kt;
    if (kt >= 1024) { Ak = A2; Bk = Bt2; kk = kt - 1024; }
#pragma unroll
    for (int j = 0; j < 2; ++j) {
      const int r0 = w * 16 + j * 64;
      gl_lds16(Ak + (size_t)(m0 + r0 + r_ld) * lda + kk + c_ld, &As[r0 * 32]);
    }
    {
      const int r0 = w * 16;
      gl_lds16(Bk + (size_t)(n0 + r0 + r_ld) * ldb + kk + c_ld, &Bs[r0 * 32]);
    }
    __syncthreads();
    bf16x8 af[2], bfr[4];
#pragma unroll
    for (int m = 0; m < 2; ++m) af[m] = *(const bf16x8*)&As[(w * 32 + m * 16 + rr) * 32 + kk8];
#pragma unroll
    for (int n = 0; n < 4; ++n) bfr[n] = *(const bf16x8*)&Bs[(n * 16 + rr) * 32 + kk8];
#pragma unroll
    for (int m = 0; m < 2; ++m)
#pragma unroll
      for (int n = 0; n < 4; ++n)
        acc[m][n] = __builtin_amdgcn_mfma_f32_16x16x32_bf16(af[m], bfr[n], acc[m][n], 0, 0, 0);
    __syncthreads();
  }

  const int rr4 = (lane >> 4) * 4, cc = lane & 15;
#pragma unroll
  for (int m = 0; m < 2; ++m)
#pragma unroll
    for (int n = 0; n < 4; ++n) {
      const int gr0 = m0 + w * 32 + m * 16 + rr4;
      const int gc = n0 + n * 16 + cc;
      const float bb = bias[gc];
#pragma unroll
      for (int i = 0; i < 4; ++i)
        __builtin_nontemporal_store(acc[m][n][i] + bb, Cout + (size_t)(gr0 + i) * ldc + gc);
    }
}

// ---------------------------------------------------------------- fused attention
// WRITE_P=1 folds phase[bh]^2 into the Q pre-scale (scores *= ph^2).
static constexpr int K_PLANE_B = 16400;
static constexpr int V_OFF_B   = 4 * K_PLANE_B;
static constexpr int V_ROW_B   = 2064;
static constexpr int P_OFF_B   = V_OFF_B + 32 * V_ROW_B;
static constexpr int P_WAVE_B  = 2304;
static constexpr int ATTN_LDS  = P_OFF_B + 8 * P_WAVE_B;  // 150080

template <int WRITE_P>
__global__ __launch_bounds__(512) void attn_fused(const bf16_t* __restrict__ Qm,
                                                  const bf16_t* __restrict__ Km, int rs,
                                                  const bf16_t* __restrict__ Vt,
                                                  float* __restrict__ Pout,
                                                  bf16_t* __restrict__ ctx,
                                                  const float* __restrict__ phase,
                                                  float scale2) {
  extern __shared__ char smem[];
  char* Kl = smem;
  char* Vl = smem + V_OFF_B;
  const int tid = threadIdx.x, lane = tid & 63, w = tid >> 6;
  const int g = lane >> 4, r = lane & 15;
  int flat = blockIdx.y * 8 + blockIdx.x;
  flat = (flat & 7) * 128 + (flat >> 3);
  const int bh = flat >> 3, xb = flat & 7;
  const int b = bh >> 5, h = bh & 31;
  char* myP = smem + P_OFF_B + w * P_WAVE_B;

  {
    const bf16_t* Kbase = Km + (size_t)b * Ss * rs + h * 32;
    const int pg = w >> 1, hh = w & 1;
#pragma unroll
    for (int c = 0; c < 8; ++c) {
      const int row0 = hh * 512 + c * 64;
      gl_lds16(Kbase + (size_t)(row0 + lane) * rs + pg * 8, Kl + pg * K_PLANE_B + row0 * 16);
    }
  }
  {
    const bf16_t* vsrc = Vt + (size_t)bh * (Dd * Ss);
#pragma unroll
    for (int rr2 = 0; rr2 < 4; ++rr2) {
      const int row = w * 4 + rr2;
#pragma unroll
      for (int c = 0; c < 2; ++c)
        gl_lds16(vsrc + (size_t)row * Ss + c * 512 + lane * 8, Vl + row * V_ROW_B + c * 1024);
    }
  }
  const int qrow0 = xb * 128 + w * 16;
  const bf16x8 qraw = *(const bf16x8*)(Qm + ((size_t)b * Ss + qrow0 + r) * rs + h * 32 + g * 8);
  float qs = scale2;
  if constexpr (WRITE_P) {
    const float ph = phase[bh];
    qs *= ph * ph;          // Q*ph, K*ph -> scores * ph^2
  }
  bf16x8 qf;
#pragma unroll
  for (int i = 0; i < 8; ++i) qf[i] = (bf16_t)((float)qraw[i] * qs);
  __syncthreads();

  const f32x4 zero = {0.f, 0.f, 0.f, 0.f};
  float lsum = 0.f, rinv = 1.f;

  if constexpr (WRITE_P) {
    for (int kt = 0; kt < 16; ++kt) {
#pragma unroll
      for (int n = 0; n < 4; ++n) {
        const int key = kt * 64 + n * 16 + r;
        const bf16x8 kf = *(const bf16x8*)(Kl + g * K_PLANE_B + key * 16);
        const f32x4 s = __builtin_amdgcn_mfma_f32_16x16x32_bf16(kf, qf, zero, 0, 0, 0);
#pragma unroll
        for (int i = 0; i < 4; ++i) lsum += fexp2(s[i]);
      }
    }
    lsum += __shfl_xor(lsum, 16);
    lsum += __shfl_xor(lsum, 32);
    rinv = 1.0f / lsum;
  }

  f32x4 acc2[2] = {zero, zero};
  const size_t pbase = (size_t)bh * Ss * Ss;

  for (int kt = 0; kt < 16; ++kt) {
    float p[4][4];
#pragma unroll
    for (int n = 0; n < 4; ++n) {
      const int key = kt * 64 + n * 16 + r;
      const bf16x8 kf = *(const bf16x8*)(Kl + g * K_PLANE_B + key * 16);
      const f32x4 s = __builtin_amdgcn_mfma_f32_16x16x32_bf16(kf, qf, zero, 0, 0, 0);
#pragma unroll
      for (int i = 0; i < 4; ++i) {
        float e = fexp2(s[i]);
        if constexpr (WRITE_P) e *= rinv;
        else lsum += e;
        p[n][i] = e;
      }
      bf16x4 pw = {(bf16_t)p[n][0], (bf16_t)p[n][1], (bf16_t)p[n][2], (bf16_t)p[n][3]};
      *(bf16x4*)(myP + r * 144 + (n * 16 + g * 4) * 2) = pw;
      if constexpr (WRITE_P) {
        f32x4 w4 = {p[n][0], p[n][1], p[n][2], p[n][3]};
        __builtin_nontemporal_store(
            w4, (f32x4*)&Pout[pbase + (size_t)(qrow0 + r) * Ss + kt * 64 + n * 16 + 4 * g]);
      }
    }
#pragma unroll
    for (int c = 0; c < 2; ++c) {
      const bf16x8 pa = *(const bf16x8*)(myP + r * 144 + (c * 32 + 8 * g) * 2);
#pragma unroll
      for (int dn = 0; dn < 2; ++dn) {
        const bf16x8 vf = *(const bf16x8*)(Vl + (dn * 16 + r) * V_ROW_B +
                                           (kt * 64 + c * 32 + g * 8) * 2);
        acc2[dn] = __builtin_amdgcn_mfma_f32_16x16x32_bf16(vf, pa, acc2[dn], 0, 0, 0);
      }
    }
  }

  if constexpr (!WRITE_P) {
    lsum += __shfl_xor(lsum, 16);
    lsum += __shfl_xor(lsum, 32);
    rinv = 1.0f / lsum;
#pragma unroll
    for (int dn = 0; dn < 2; ++dn)
#pragma unroll
      for (int i = 0; i < 4; ++i) acc2[dn][i] *= rinv;
  }

  float* Ct = (float*)myP;
#pragma unroll
  for (int dn = 0; dn < 2; ++dn)
#pragma unroll
    for (int i = 0; i < 4; ++i)
      Ct[r * 36 + dn * 16 + 4 * g + i] = acc2[dn][i];
  const int q2 = lane >> 2, pt = lane & 3;
  const f32x4 ca = *(const f32x4*)(myP + q2 * 144 + pt * 32);
  const f32x4 cb = *(const f32x4*)(myP + q2 * 144 + pt * 32 + 16);
  bf16x8 cv = {(bf16_t)ca[0], (bf16_t)ca[1], (bf16_t)ca[2], (bf16_t)ca[3],
               (bf16_t)cb[0], (bf16_t)cb[1], (bf16_t)cb[2], (bf16_t)cb[3]};
  *(bf16x8*)&ctx[((size_t)b * Ss + qrow0 + q2) * Ee + h * 32 + pt * 8] = cv;
}

// ================================================================ launcher
extern "C" void kernel_launch(void* const* d_in, const int* in_sizes, int n_in,
                              void* d_out, int out_size, void* d_ws, size_t ws_size,
                              hipStream_t stream) {
  const float* x     = (const float*)d_in[0];
  const float* q_w   = (const float*)d_in[1];
  const float* q_b   = (const float*)d_in[2];
  const float* k_w   = (const float*)d_in[3];
  const float* k_b   = (const float*)d_in[4];
  const float* v_w   = (const float*)d_in[5];
  const float* v_b   = (const float*)d_in[6];
  const float* ph_w1 = (const float*)d_in[7];
  const float* ph_b1 = (const float*)d_in[8];
  const float* ph_w2 = (const float*)d_in[9];
  const float* ph_b2 = (const float*)d_in[10];
  const float* in_w  = (const float*)d_in[11];
  const float* in_b  = (const float*)d_in[12];
  const float* out_w = (const float*)d_in[13];
  const float* out_b = (const float*)d_in[14];
  const float* fin_w = (const float*)d_in[15];
  const float* fin_b = (const float*)d_in[16];

  float* outp = (float*)d_out;
  float* attn_out = outp + (size_t)Ntok * Ee;

  char* ws = (char*)d_ws;
  size_t off = 0;
  auto alloc = [&](size_t bytes) -> void* {
    void* p = ws + off;
    off += (bytes + 255) & ~(size_t)255;
    return p;
  };
  bf16_t* x_bf  = (bf16_t*)alloc((size_t)Ntok * Ee * 2);
  bf16_t* wqkv  = (bf16_t*)alloc((size_t)E3 * Ee * 2);
  bf16_t* win   = (bf16_t*)alloc((size_t)E3 * Ee * 2);
  bf16_t* wout  = (bf16_t*)alloc((size_t)Ee * Ee * 2);
  bf16_t* wfin  = (bf16_t*)alloc((size_t)Ee * Ee * 2);
  bf16_t* woutT = (bf16_t*)alloc((size_t)Ee * Ee * 2);
  bf16_t* Wc    = (bf16_t*)alloc((size_t)Ee * Ee * 2);
  bf16_t* QKVb  = (bf16_t*)alloc((size_t)Ntok * E3 * 2);
  bf16_t* Vt    = (bf16_t*)alloc((size_t)Bb * Hh * Dd * Ss * 2);
  bf16_t* ctx   = (bf16_t*)alloc((size_t)Ntok * Ee * 2);
  bf16_t* qkv2  = (bf16_t*)alloc((size_t)Ntok * E3 * 2);
  bf16_t* v2t   = (bf16_t*)alloc((size_t)Bb * Hh * Dd * Ss * 2);
  bf16_t* ctx2  = (bf16_t*)alloc((size_t)Ntok * Ee * 2);
  float* part   = (float*)alloc((size_t)32 * 4 * 1024 * 4);
  float* xmean  = (float*)alloc(4096 * 4);
  float* hb     = (float*)alloc(4096 * 4);
  float* phase  = (float*)alloc(128 * 4);
  float* qkvb   = (float*)alloc(3072 * 4);
  float* bias_c = (float*)alloc(1024 * 4);

  hipFuncSetAttribute((const void*)attn_fused<1>,
                      hipFuncAttributeMaxDynamicSharedMemorySize, ATTN_LDS);
  hipFuncSetAttribute((const void*)attn_fused<0>,
                      hipFuncAttributeMaxDynamicSharedMemorySize, ATTN_LDS);

  // 1. mega-prep
  prep<<<12492, 256, 0, stream>>>(x, q_w, k_w, v_w, in_w, out_w, fin_w,
                                  q_b, k_b, v_b, out_b, fin_b,
                                  x_bf, wqkv, win, wout, wfin, qkvb, bias_c, part);
  // 2. colmean finish + wout transpose (merged)
  fin_t1024<<<272, 256, 0, stream>>>(part, xmean, wout, woutT);
  // 3. QKV projection + Wc GEMM (merged; phase now applied inside attn1)
  qkv_wc<<<896, 256, 0, stream>>>(x_bf, wqkv, qkvb, QKVb, Vt, wfin, woutT, Wc);
  // 4-5. phase chain tail
  hgemm<<<64, 256, 0, stream>>>(xmean, ph_w1, ph_b1, hb);
  phasek<<<128, 64, 0, stream>>>(hb, ph_w2, ph_b2, phase);
  // 6. attention 1 (phase^2 folded into Q scale; P -> d_out + fused PV)
  attn_fused<1><<<dim3(8, 128), 512, ATTN_LDS, stream>>>(QKVb, QKVb + 1024, E3, Vt,
                                                         attn_out, ctx, phase, SCALE2);
  // 7. in_proj; V2 written transposed straight to v2t
  gemm_bt<<<dim3(24, 32), 256, 0, stream>>>(ctx, win, in_b, qkv2, v2t, 1024, Ee, Ee, E3);
  // 8. attention 2 (flash)
  attn_fused<0><<<dim3(8, 128), 512, ATTN_LDS, stream>>>(qkv2, qkv2 + 1024, E3, v2t,
                                                         nullptr, ctx2, nullptr, SCALE2);
  // 9. fused out_proj+residual+final: outp = ctx2@Wc^T + ctx@fin_w^T + bias_c
  gemm_fin<<<dim3(16, 32), 256, 0, stream>>>(ctx2, ctx, Wc, wfin, bias_c,
                                             outp, 2048, Ee, Ee, Ee);
}